// Round 3
// baseline (815.074 us; speedup 1.0000x reference)
//
#include <hip/hip_runtime.h>
#include <hip/hip_bf16.h>

#define B_ 8
#define T_ 2048
#define C_ 1024
#define S_ 1024      // top_k == reduced sequence length
#define H_ 16
#define DH_ 64
#define DFF_ 4096
#define M_ (B_*S_)   // 8192 rows through the block
#define CHUNKB 2     // batches per attention chunk (scores buffer = 64MB)

typedef __attribute__((ext_vector_type(8))) short bf16x8;
typedef __attribute__((ext_vector_type(4))) float f32x4;

__device__ __forceinline__ short f2bf(float f) {
  __hip_bfloat16 h = __float2bfloat16(f);
  return *reinterpret_cast<short*>(&h);
}
__device__ __forceinline__ float bf2f(short s) {
  __hip_bfloat16 h = *reinterpret_cast<__hip_bfloat16*>(&s);
  return __bfloat162float(h);
}

typedef const __attribute__((address_space(1))) unsigned int* gas_p;
typedef __attribute__((address_space(3))) unsigned int* las_p;
__device__ __forceinline__ void gload_lds16(const void* g, void* l) {
  __builtin_amdgcn_global_load_lds((gas_p)g, (las_p)l, 16, 0, 0);
}

// ---------------- router logits: one wave per token ----------------
__global__ __launch_bounds__(256) void k_router(const float* __restrict__ x,
    const float* __restrict__ wr, float* __restrict__ logits) {
  int tok = blockIdx.x * 4 + (threadIdx.x >> 6);
  int l = threadIdx.x & 63;
  const float* xr = x + (size_t)tok * C_;
  float s = 0.f;
  #pragma unroll
  for (int j = 0; j < C_/64; ++j) s += xr[l + 64*j] * wr[l + 64*j];
  #pragma unroll
  for (int m = 32; m; m >>= 1) s += __shfl_xor(s, m);
  if (l == 0) logits[tok] = s;
}

// ------------- exact top-k via bitonic sort (1 block / batch) -------------
__global__ __launch_bounds__(1024) void k_topk(const float* __restrict__ logits,
    int* __restrict__ idx, float* __restrict__ wts) {
  __shared__ unsigned long long key[2048];
  int b = blockIdx.x, t = threadIdx.x;
  for (int i = t; i < T_; i += 1024) {
    float v = logits[(size_t)b*T_ + i];
    unsigned u = __float_as_uint(v);
    unsigned so = u ^ ((u >> 31) ? 0xFFFFFFFFu : 0x80000000u);
    key[i] = ((unsigned long long)(~so) << 32) | (unsigned)i;
  }
  __syncthreads();
  for (int k = 2; k <= 2048; k <<= 1) {
    for (int j = k >> 1; j > 0; j >>= 1) {
      int i = ((t & ~(j-1)) << 1) | (t & (j-1));
      int ix = i | j;
      unsigned long long a = key[i], c = key[ix];
      bool up = ((i & k) == 0);
      if ((a > c) == up) { key[i] = c; key[ix] = a; }
      __syncthreads();
    }
  }
  unsigned long long a = key[t];
  __syncthreads();
  unsigned i0 = (unsigned)(a & 0xFFFFFFFFu);
  unsigned so = ~(unsigned)(a >> 32);
  unsigned bits = (so & 0x80000000u) ? (so ^ 0x80000000u) : ~so;
  key[t] = ((unsigned long long)i0 << 32) | bits;
  __syncthreads();
  for (int k = 2; k <= 1024; k <<= 1) {
    for (int j = k >> 1; j > 0; j >>= 1) {
      if (t < 512) {
        int i = ((t & ~(j-1)) << 1) | (t & (j-1));
        int ix = i | j;
        unsigned long long a2 = key[i], c2 = key[ix];
        bool up = ((i & k) == 0);
        if ((a2 > c2) == up) { key[i] = c2; key[ix] = a2; }
      }
      __syncthreads();
    }
  }
  idx[(size_t)b*S_ + t] = (int)(key[t] >> 32);
  wts[(size_t)b*S_ + t] = __uint_as_float((unsigned)(key[t] & 0xFFFFFFFFu));
}

// -------- fp32 -> bf16 conversion (weights) --------
__global__ __launch_bounds__(256) void k_cvt(const float* __restrict__ s,
    short* __restrict__ d, int n4) {
  int i = blockIdx.x * 256 + threadIdx.x;
  if (i >= n4) return;
  float4 v = ((const float4*)s)[i];
  short4 o;
  o.x = f2bf(v.x); o.y = f2bf(v.y); o.z = f2bf(v.z); o.w = f2bf(v.w);
  ((short4*)d)[i] = o;
}

// -------- LayerNorm (optionally gathering tokens from x via idx) --------
template<bool GATHER>
__global__ __launch_bounds__(256) void k_ln(const float* __restrict__ x,
    const int* __restrict__ idx, float* __restrict__ hbuf,
    short* __restrict__ obf, const float* __restrict__ g,
    const float* __restrict__ beta) {
  __shared__ float red[8];
  int row = blockIdx.x;
  const float* src;
  if (GATHER) {
    int b = row >> 10, k = row & 1023;
    src = x + ((size_t)b*T_ + idx[b*S_ + k]) * C_;
  } else {
    src = hbuf + (size_t)row * C_;
  }
  int t = threadIdx.x;
  float4 v = *(const float4*)(src + t*4);
  float s  = v.x + v.y + v.z + v.w;
  float s2 = v.x*v.x + v.y*v.y + v.z*v.z + v.w*v.w;
  #pragma unroll
  for (int m = 32; m; m >>= 1) { s += __shfl_xor(s, m); s2 += __shfl_xor(s2, m); }
  int w = t >> 6, lane = t & 63;
  if (lane == 0) { red[w] = s; red[w+4] = s2; }
  __syncthreads();
  s  = red[0]+red[1]+red[2]+red[3];
  s2 = red[4]+red[5]+red[6]+red[7];
  float mu = s * (1.f/(float)C_);
  float var = s2 * (1.f/(float)C_) - mu*mu;
  float rs = rsqrtf(var + 1e-5f);
  int c0 = t*4;
  float4 gw = *(const float4*)(g + c0);
  float4 bw = *(const float4*)(beta + c0);
  short4 o;
  o.x = f2bf((v.x-mu)*rs*gw.x + bw.x);
  o.y = f2bf((v.y-mu)*rs*gw.y + bw.y);
  o.z = f2bf((v.z-mu)*rs*gw.z + bw.z);
  o.w = f2bf((v.w-mu)*rs*gw.w + bw.w);
  *(short4*)(obf + (size_t)row*C_ + c0) = o;
  if (GATHER) *(float4*)(hbuf + (size_t)row*C_ + c0) = v;
}

#define EPI_BF16 0
#define EPI_GELU 1
#define EPI_ADD32 2

__device__ __forceinline__ float gelu_exact(float v) {
  return 0.5f*v*(1.f + erff(v*0.70710678118654752f));
}

// -------- old 128-tile GEMM (attention: scores / PV) --------
template<int BM, int BN, int EPI, bool SKIPUP, bool CAUSK>
__global__ __launch_bounds__(256) void k_gemm(
    const short* __restrict__ A, int lda,
    const short* __restrict__ Bp, int ldb,
    void* __restrict__ Cp, int ldc,
    const float* __restrict__ bias,
    int N, int Ktot, int zdiv,
    long long azo, long long azi, long long bzo, long long bzi,
    long long czo, long long czi) {
  __shared__ short As[BM*32];
  __shared__ short Bs[BN*32];
  int z = blockIdx.z;
  int zo = z / zdiv, zi = z % zdiv;
  const short* Ab = A + zo*azo + zi*azi;
  const short* Bb = Bp + zo*bzo + zi*bzi;
  long long coff = zo*czo + zi*czi;
  int nt = N / BN;
  int bm = blockIdx.x / nt, bn = blockIdx.x % nt;
  if (SKIPUP && bn*BN > bm*BM + (BM-1)) return;
  int kend = CAUSK ? (bm*BM + BM < Ktot ? bm*BM + BM : Ktot) : Ktot;
  const short* Ar = Ab + (size_t)bm*BM*lda;
  const short* Br = Bb + (size_t)bn*BN*ldb;
  constexpr int WM = BM/2, WN = BN/2, FM = WM/16, FN = WN/16;
  int t = threadIdx.x, lane = t & 63, w = t >> 6;
  int wm = w >> 1, wn = w & 1;
  int lr = lane & 15, lk = (lane >> 4) << 3;
  f32x4 acc[FM][FN] = {};
  for (int k0 = 0; k0 < kend; k0 += 32) {
    #pragma unroll
    for (int c = 0; c < BM/64; ++c) {
      int e = (c*256 + t)*8;
      gload_lds16(Ar + (size_t)(e >> 5)*lda + (k0 + (e & 31)), &As[e]);
    }
    #pragma unroll
    for (int c = 0; c < BN/64; ++c) {
      int e = (c*256 + t)*8;
      gload_lds16(Br + (size_t)(e >> 5)*ldb + (k0 + (e & 31)), &Bs[e]);
    }
    asm volatile("s_waitcnt vmcnt(0)" ::: "memory");
    __syncthreads();
    bf16x8 af[FM], bfv[FN];
    #pragma unroll
    for (int i = 0; i < FM; ++i)
      af[i] = *(const bf16x8*)&As[(wm*WM + i*16 + lr)*32 + lk];
    #pragma unroll
    for (int j = 0; j < FN; ++j)
      bfv[j] = *(const bf16x8*)&Bs[(wn*WN + j*16 + lr)*32 + lk];
    #pragma unroll
    for (int i = 0; i < FM; ++i)
      #pragma unroll
      for (int j = 0; j < FN; ++j)
        acc[i][j] = __builtin_amdgcn_mfma_f32_16x16x32_bf16(bfv[j], af[i], acc[i][j], 0, 0, 0);
    __syncthreads();
  }
  int mrow0 = bm*BM + wm*WM + lr;
  int ncol0 = bn*BN + wn*WN + ((lane >> 4) << 2);
  #pragma unroll
  for (int i = 0; i < FM; ++i) {
    int row = mrow0 + i*16;
    #pragma unroll
    for (int j = 0; j < FN; ++j) {
      int col = ncol0 + j*16;
      float4 bv = bias ? *(const float4*)(bias + col) : make_float4(0.f,0.f,0.f,0.f);
      float v0 = acc[i][j][0] + bv.x, v1 = acc[i][j][1] + bv.y;
      float v2 = acc[i][j][2] + bv.z, v3 = acc[i][j][3] + bv.w;
      if (EPI == EPI_ADD32) {
        float* Co = (float*)Cp + coff + (size_t)row*ldc + col;
        float4 old = *(float4*)Co;
        old.x += v0; old.y += v1; old.z += v2; old.w += v3;
        *(float4*)Co = old;
      } else {
        if (EPI == EPI_GELU) {
          v0 = gelu_exact(v0); v1 = gelu_exact(v1);
          v2 = gelu_exact(v2); v3 = gelu_exact(v3);
        }
        short4 o; o.x = f2bf(v0); o.y = f2bf(v1); o.z = f2bf(v2); o.w = f2bf(v3);
        *(short4*)((short*)Cp + coff + (size_t)row*ldc + col) = o;
      }
    }
  }
}

// ======== k_gemm3: 256-row tile, BK=64, counted-vmcnt deep pipeline ========
// Schedule per K-tile (buf = kt&1):
//   [plain ds_reads of all 24(20) frags + MFMA ks0]   (compiler fine-interleaves)
//   lgkmcnt(0); sched_barrier; s_barrier          <- all waves done READING buf
//   stage(kt+2 -> buf)  ||  MFMA ks1              <- write-after-read safe
//   vmcnt(NLD) [or vmcnt(0) if nothing staged]    <- tile kt+1 fully landed
//   s_barrier                                     <- safe to read buf^1
// Prefetch distance 2; vmcnt never drains to 0 in steady state (T3+T4).
template<int BM, int BN, int EPI>
__global__ __launch_bounds__(512, 2) void k_gemm3(
    const short* __restrict__ A, int lda,
    const short* __restrict__ Bp, int ldb,
    void* __restrict__ Cp, int ldc,
    const float* __restrict__ bias,
    int nNt, int Ktot) {
  constexpr int LDA_CH = BM/64, LDB_CH = BN/64, NLD = LDA_CH + LDB_CH;
  __shared__ short As[2][BM*64];
  __shared__ short Bs[2][BN*64];
  // T1: bijective XCD swizzle (m204)
  int nwg = gridDim.x, orig = blockIdx.x;
  int q8 = nwg >> 3, r8 = nwg & 7;
  int xcd = orig & 7, loc = orig >> 3;
  int wg = (xcd < r8 ? xcd*(q8+1) : r8*(q8+1) + (xcd-r8)*q8) + loc;
  int bm = wg / nNt, bn = wg % nNt;
  const short* Ar = A + (size_t)bm*BM*lda;
  const short* Br = Bp + (size_t)bn*BN*ldb;
  int t = threadIdx.x, lane = t & 63, w = t >> 6;
  int wm = w >> 2, wn = w & 3;
  int lr = lane & 15, kq = lane >> 4;
  constexpr int WM = BM/2, WN = BN/4, FM = WM/16, FN = WN/16;

  auto stage = [&](int buf, int k0) {
    #pragma unroll
    for (int c = 0; c < LDA_CH; ++c) {
      int ch = c*512 + t;
      int row = ch >> 3, sq = (ch & 7) ^ (row & 7);
      gload_lds16(Ar + (size_t)row*lda + (k0 + sq*8), &As[buf][ch*8]);
    }
    #pragma unroll
    for (int c = 0; c < LDB_CH; ++c) {
      int ch = c*512 + t;
      int row = ch >> 3, sq = (ch & 7) ^ (row & 7);
      gload_lds16(Br + (size_t)row*ldb + (k0 + sq*8), &Bs[buf][ch*8]);
    }
  };

  f32x4 acc[FM][FN] = {};
  int NT = Ktot >> 6;
  stage(0, 0);
  stage(1, 64);
  asm volatile("s_waitcnt vmcnt(%0)" :: "n"(NLD) : "memory");  // tile 0 landed
  __builtin_amdgcn_s_barrier();
  for (int kt = 0; kt < NT; ++kt) {
    const short* Abf = As[kt & 1];
    const short* Bbf = Bs[kt & 1];
    bf16x8 af[2][FM], bfv[2][FN];
    #pragma unroll
    for (int ks = 0; ks < 2; ++ks) {
      #pragma unroll
      for (int i = 0; i < FM; ++i) {
        int ra = wm*WM + i*16 + lr;
        af[ks][i] = *(const bf16x8*)&Abf[ra*64 + ((((ks<<2)+kq) ^ (ra & 7)) << 3)];
      }
      #pragma unroll
      for (int j = 0; j < FN; ++j) {
        int rb = wn*WN + j*16 + lr;
        bfv[ks][j] = *(const bf16x8*)&Bbf[rb*64 + ((((ks<<2)+kq) ^ (rb & 7)) << 3)];
      }
    }
    #pragma unroll
    for (int i = 0; i < FM; ++i)
      #pragma unroll
      for (int j = 0; j < FN; ++j)
        acc[i][j] = __builtin_amdgcn_mfma_f32_16x16x32_bf16(bfv[0][j], af[0][i], acc[i][j], 0, 0, 0);
    asm volatile("s_waitcnt lgkmcnt(0)" ::: "memory");
    __builtin_amdgcn_sched_barrier(0);
    __builtin_amdgcn_s_barrier();              // all waves done reading buf
    bool more = (kt + 2 < NT);
    if (more) stage(kt & 1, (kt + 2) << 6);    // overlaps with ks1 MFMAs below
    #pragma unroll
    for (int i = 0; i < FM; ++i)
      #pragma unroll
      for (int j = 0; j < FN; ++j)
        acc[i][j] = __builtin_amdgcn_mfma_f32_16x16x32_bf16(bfv[1][j], af[1][i], acc[i][j], 0, 0, 0);
    if (kt + 1 < NT) {
      if (more) asm volatile("s_waitcnt vmcnt(%0)" :: "n"(NLD) : "memory");
      else      asm volatile("s_waitcnt vmcnt(0)" ::: "memory");
      __builtin_amdgcn_s_barrier();            // tile kt+1 ready for everyone
    }
  }
  // packed swapped epilogue (same layout as k_gemm, verified)
  int mrow0 = bm*BM + wm*WM + lr;
  int ncol0 = bn*BN + wn*WN + (kq << 2);
  #pragma unroll
  for (int i = 0; i < FM; ++i) {
    int row = mrow0 + i*16;
    #pragma unroll
    for (int j = 0; j < FN; ++j) {
      int col = ncol0 + j*16;
      float4 bv = bias ? *(const float4*)(bias + col) : make_float4(0.f,0.f,0.f,0.f);
      float v0 = acc[i][j][0] + bv.x, v1 = acc[i][j][1] + bv.y;
      float v2 = acc[i][j][2] + bv.z, v3 = acc[i][j][3] + bv.w;
      if (EPI == EPI_ADD32) {
        float* Co = (float*)Cp + (size_t)row*ldc + col;
        float4 old = *(float4*)Co;
        old.x += v0; old.y += v1; old.z += v2; old.w += v3;
        *(float4*)Co = old;
      } else {
        if (EPI == EPI_GELU) {
          v0 = gelu_exact(v0); v1 = gelu_exact(v1);
          v2 = gelu_exact(v2); v3 = gelu_exact(v3);
        }
        short4 o; o.x = f2bf(v0); o.y = f2bf(v1); o.z = f2bf(v2); o.w = f2bf(v3);
        *(short4*)((short*)Cp + (size_t)row*ldc + col) = o;
      }
    }
  }
}

// -------- V transpose: qkv[b,s,2C+h*64+d] -> vt[(b*H+h)*64+d][s] --------
__global__ __launch_bounds__(256) void k_vt(const short* __restrict__ qkv,
                                            short* __restrict__ vt) {
  __shared__ short tile[64][65];
  int blk = blockIdx.x;
  int s0 = (blk & 15) << 6;
  int bh = blk >> 4;
  int b = bh >> 4, h = bh & 15;
  const short* src = qkv + (size_t)b*S_*3*C_ + 2*C_ + h*DH_;
  int t = threadIdx.x;
  #pragma unroll
  for (int it = 0; it < 16; ++it) {
    int e = it*256 + t;
    int r = e >> 6, d = e & 63;
    tile[d][r] = src[(size_t)(s0 + r)*3*C_ + d];
  }
  __syncthreads();
  short* dst = vt + (size_t)bh*DH_*S_ + s0;
  #pragma unroll
  for (int it = 0; it < 16; ++it) {
    int e = it*256 + t;
    int d2 = e >> 6, c = e & 63;
    dst[(size_t)d2*S_ + c] = tile[d2][c];
  }
}

// -------- causal softmax, one block per row, vectorized bf16x4 I/O --------
__global__ __launch_bounds__(256) void k_softmax(short* __restrict__ sc) {
  __shared__ float red[4];
  int rowg = blockIdx.x;
  int q = rowg & (S_-1);
  short* p = sc + (size_t)rowg * S_;
  int t = threadIdx.x;
  short4 s4 = ((const short4*)p)[t];
  int c0 = t*4;
  float v[4] = { bf2f(s4.x)*0.125f, bf2f(s4.y)*0.125f,
                 bf2f(s4.z)*0.125f, bf2f(s4.w)*0.125f };
  float mx = -3.0e38f;
  #pragma unroll
  for (int i = 0; i < 4; ++i) {
    v[i] = (c0 + i <= q) ? v[i] : -3.0e38f;
    mx = fmaxf(mx, v[i]);
  }
  #pragma unroll
  for (int m = 32; m; m >>= 1) mx = fmaxf(mx, __shfl_xor(mx, m));
  int w = t >> 6, lane = t & 63;
  if (lane == 0) red[w] = mx;
  __syncthreads();
  mx = fmaxf(fmaxf(red[0], red[1]), fmaxf(red[2], red[3]));
  __syncthreads();
  float sum = 0.f;
  #pragma unroll
  for (int i = 0; i < 4; ++i) {
    v[i] = (v[i] > -1.0e38f) ? expf(v[i] - mx) : 0.f;
    sum += v[i];
  }
  #pragma unroll
  for (int m = 32; m; m >>= 1) sum += __shfl_xor(sum, m);
  if (lane == 0) red[w] = sum;
  __syncthreads();
  sum = red[0] + red[1] + red[2] + red[3];
  float inv = 1.f / sum;
  short4 o;
  o.x = f2bf(v[0]*inv); o.y = f2bf(v[1]*inv);
  o.z = f2bf(v[2]*inv); o.w = f2bf(v[3]*inv);
  ((short4*)p)[t] = o;
}

// -------- out = x everywhere --------
__global__ void k_copy(const float* __restrict__ src, float* __restrict__ dst,
                       size_t n4) {
  size_t i = (size_t)blockIdx.x*256 + threadIdx.x;
  size_t stride = (size_t)gridDim.x*256;
  for (; i < n4; i += stride) ((float4*)dst)[i] = ((const float4*)src)[i];
}

// -------- out[selected row] = x + weight * h --------
__global__ __launch_bounds__(256) void k_scatter(const float* __restrict__ x,
    const int* __restrict__ idx, const float* __restrict__ wts,
    const float* __restrict__ hbuf, float* __restrict__ out) {
  int row = blockIdx.x;
  int b = row >> 10, k = row & 1023;
  int tk = idx[(size_t)b*S_ + k];
  float wv = wts[(size_t)b*S_ + k];
  size_t o  = ((size_t)b*T_ + tk)*C_ + threadIdx.x*4;
  size_t hs = (size_t)row*C_ + threadIdx.x*4;
  float4 xv = *(const float4*)(x + o);
  float4 hv = *(const float4*)(hbuf + hs);
  xv.x += wv*hv.x; xv.y += wv*hv.y; xv.z += wv*hv.z; xv.w += wv*hv.w;
  *(float4*)(out + o) = xv;
}

extern "C" void kernel_launch(void* const* d_in, const int* in_sizes, int n_in,
                              void* d_out, int out_size, void* d_ws, size_t ws_size,
                              hipStream_t stream) {
  const float* x     = (const float*)d_in[0];
  const float* wrt   = (const float*)d_in[1];
  const float* ln1w  = (const float*)d_in[2];
  const float* ln1b  = (const float*)d_in[3];
  const float* wqkv  = (const float*)d_in[4];
  const float* bqkv  = (const float*)d_in[5];
  const float* wo    = (const float*)d_in[6];
  const float* bo    = (const float*)d_in[7];
  const float* ln2w  = (const float*)d_in[8];
  const float* ln2b  = (const float*)d_in[9];
  const float* wfc   = (const float*)d_in[10];
  const float* bfc   = (const float*)d_in[11];
  const float* wproj = (const float*)d_in[12];
  const float* bproj = (const float*)d_in[13];
  float* out = (float*)d_out;

  char* p = (char*)d_ws;
  auto alloc = [&](size_t bytes) {
    char* r = p; p += (bytes + 255) & ~(size_t)255; return r;
  };
  float* logits = (float*)alloc((size_t)B_*T_*4);
  int*   idx    = (int*)  alloc((size_t)B_*S_*4);
  float* wts    = (float*)alloc((size_t)B_*S_*4);
  float* hbuf   = (float*)alloc((size_t)M_*C_*4);
  short* abuf   = (short*)alloc((size_t)M_*C_*2);
  short* qkvb   = (short*)alloc((size_t)M_*3*C_*2);
  short* vtb    = (short*)alloc((size_t)B_*H_*DH_*S_*2);
  short* attnb  = (short*)alloc((size_t)M_*C_*2);
  short* fcb    = (short*)alloc((size_t)M_*DFF_*2);
  short* wqkvb  = (short*)alloc((size_t)3*C_*C_*2);
  short* wob    = (short*)alloc((size_t)C_*C_*2);
  short* wfcb   = (short*)alloc((size_t)DFF_*C_*2);
  short* wprojb = (short*)alloc((size_t)C_*DFF_*2);
  short* scb = fcb;
  if (ws_size < (size_t)(p - (char*)d_ws)) return;

  k_cvt<<<dim3(3*C_*C_/4/256), dim3(256), 0, stream>>>(wqkv, wqkvb, 3*C_*C_/4);
  k_cvt<<<dim3(C_*C_/4/256),   dim3(256), 0, stream>>>(wo, wob, C_*C_/4);
  k_cvt<<<dim3(DFF_*C_/4/256), dim3(256), 0, stream>>>(wfc, wfcb, DFF_*C_/4);
  k_cvt<<<dim3(C_*DFF_/4/256), dim3(256), 0, stream>>>(wproj, wprojb, C_*DFF_/4);

  k_router<<<dim3(B_*T_/4), dim3(256), 0, stream>>>(x, wrt, logits);
  k_topk<<<dim3(B_), dim3(1024), 0, stream>>>(logits, idx, wts);

  k_ln<true><<<dim3(M_), dim3(256), 0, stream>>>(x, idx, hbuf, abuf, ln1w, ln1b);

  // QKV: [8192,1024] @ [3072,1024]^T
  k_gemm3<256,256,EPI_BF16><<<dim3((M_/256)*(3*C_/256)), dim3(512), 0, stream>>>(
      abuf, C_, wqkvb, C_, qkvb, 3*C_, bqkv, 3*C_/256, C_);

  k_vt<<<dim3(B_*H_*(S_/64)), dim3(256), 0, stream>>>(qkvb, vtb);

  for (int b0 = 0; b0 < B_; b0 += CHUNKB) {
    k_gemm<128,128,EPI_BF16,true,false>
      <<<dim3((S_/128)*(S_/128), 1, CHUNKB*H_), dim3(256), 0, stream>>>(
        qkvb + (size_t)b0*S_*3*C_, 3*C_,
        qkvb + (size_t)b0*S_*3*C_ + C_, 3*C_,
        scb, S_, nullptr, S_, DH_, H_,
        (long long)S_*3*C_, (long long)DH_,
        (long long)S_*3*C_, (long long)DH_,
        (long long)H_*S_*S_, (long long)S_*S_);
    k_softmax<<<dim3(CHUNKB*H_*S_), dim3(256), 0, stream>>>(scb);
    k_gemm<128,64,EPI_BF16,false,true>
      <<<dim3((S_/128)*(DH_/64), 1, CHUNKB*H_), dim3(256), 0, stream>>>(
        scb, S_,
        vtb + (size_t)b0*H_*DH_*S_, S_,
        attnb + (size_t)b0*S_*C_, C_, nullptr, DH_, S_, H_,
        (long long)H_*S_*S_, (long long)S_*S_,
        (long long)H_*DH_*S_, (long long)DH_*S_,
        (long long)S_*C_, (long long)DH_);
  }

  // h += attn @ w_o^T + b_o   (N=1024 -> BN=128 keeps 256 blocks = full chip)
  k_gemm3<256,128,EPI_ADD32><<<dim3((M_/256)*(C_/128)), dim3(512), 0, stream>>>(
      attnb, C_, wob, C_, hbuf, C_, bo, C_/128, C_);

  k_ln<false><<<dim3(M_), dim3(256), 0, stream>>>(nullptr, nullptr, hbuf, abuf, ln2w, ln2b);

  // fc = gelu(m @ w_fc^T + b_fc)
  k_gemm3<256,256,EPI_GELU><<<dim3((M_/256)*(DFF_/256)), dim3(512), 0, stream>>>(
      abuf, C_, wfcb, C_, fcb, DFF_, bfc, DFF_/256, C_);

  // h += fc @ w_proj^T + b_proj
  k_gemm3<256,128,EPI_ADD32><<<dim3((M_/256)*(C_/128)), dim3(512), 0, stream>>>(
      fcb, DFF_, wprojb, DFF_, hbuf, C_, bproj, C_/128, DFF_);

  k_copy<<<dim3(2048), dim3(256), 0, stream>>>(x, out, (size_t)B_*T_*C_/4);
  k_scatter<<<dim3(M_), dim3(256), 0, stream>>>(x, idx, wts, hbuf, out);
}

// Round 4
// 786.572 us; speedup vs baseline: 1.0362x; 1.0362x over previous
//
#include <hip/hip_runtime.h>
#include <hip/hip_bf16.h>

#define B_ 8
#define T_ 2048
#define C_ 1024
#define S_ 1024      // top_k == reduced sequence length
#define H_ 16
#define DH_ 64
#define DFF_ 4096
#define M_ (B_*S_)   // 8192 rows through the block
#define CHUNKB 2     // batches per attention chunk (scores buffer = 64MB)

typedef __attribute__((ext_vector_type(8))) short bf16x8;
typedef __attribute__((ext_vector_type(4))) float f32x4;

__device__ __forceinline__ short f2bf(float f) {
  __hip_bfloat16 h = __float2bfloat16(f);
  return *reinterpret_cast<short*>(&h);
}
__device__ __forceinline__ float bf2f(short s) {
  __hip_bfloat16 h = *reinterpret_cast<__hip_bfloat16*>(&s);
  return __bfloat162float(h);
}

typedef const __attribute__((address_space(1))) unsigned int* gas_p;
typedef __attribute__((address_space(3))) unsigned int* las_p;
__device__ __forceinline__ void gload_lds16(const void* g, void* l) {
  __builtin_amdgcn_global_load_lds((gas_p)g, (las_p)l, 16, 0, 0);
}

// ---------------- router logits: one wave per token ----------------
__global__ __launch_bounds__(256) void k_router(const float* __restrict__ x,
    const float* __restrict__ wr, float* __restrict__ logits) {
  int tok = blockIdx.x * 4 + (threadIdx.x >> 6);
  int l = threadIdx.x & 63;
  const float* xr = x + (size_t)tok * C_;
  float s = 0.f;
  #pragma unroll
  for (int j = 0; j < C_/64; ++j) s += xr[l + 64*j] * wr[l + 64*j];
  #pragma unroll
  for (int m = 32; m; m >>= 1) s += __shfl_xor(s, m);
  if (l == 0) logits[tok] = s;
}

// ------------- exact top-k via bitonic sort (1 block / batch) -------------
__global__ __launch_bounds__(1024) void k_topk(const float* __restrict__ logits,
    int* __restrict__ idx, float* __restrict__ wts) {
  __shared__ unsigned long long key[2048];
  int b = blockIdx.x, t = threadIdx.x;
  for (int i = t; i < T_; i += 1024) {
    float v = logits[(size_t)b*T_ + i];
    unsigned u = __float_as_uint(v);
    unsigned so = u ^ ((u >> 31) ? 0xFFFFFFFFu : 0x80000000u);
    key[i] = ((unsigned long long)(~so) << 32) | (unsigned)i;
  }
  __syncthreads();
  for (int k = 2; k <= 2048; k <<= 1) {
    for (int j = k >> 1; j > 0; j >>= 1) {
      int i = ((t & ~(j-1)) << 1) | (t & (j-1));
      int ix = i | j;
      unsigned long long a = key[i], c = key[ix];
      bool up = ((i & k) == 0);
      if ((a > c) == up) { key[i] = c; key[ix] = a; }
      __syncthreads();
    }
  }
  unsigned long long a = key[t];
  __syncthreads();
  unsigned i0 = (unsigned)(a & 0xFFFFFFFFu);
  unsigned so = ~(unsigned)(a >> 32);
  unsigned bits = (so & 0x80000000u) ? (so ^ 0x80000000u) : ~so;
  key[t] = ((unsigned long long)i0 << 32) | bits;
  __syncthreads();
  for (int k = 2; k <= 1024; k <<= 1) {
    for (int j = k >> 1; j > 0; j >>= 1) {
      if (t < 512) {
        int i = ((t & ~(j-1)) << 1) | (t & (j-1));
        int ix = i | j;
        unsigned long long a2 = key[i], c2 = key[ix];
        bool up = ((i & k) == 0);
        if ((a2 > c2) == up) { key[i] = c2; key[ix] = a2; }
      }
      __syncthreads();
    }
  }
  idx[(size_t)b*S_ + t] = (int)(key[t] >> 32);
  wts[(size_t)b*S_ + t] = __uint_as_float((unsigned)(key[t] & 0xFFFFFFFFu));
}

// -------- fp32 -> bf16 conversion (weights) --------
__global__ __launch_bounds__(256) void k_cvt(const float* __restrict__ s,
    short* __restrict__ d, int n4) {
  int i = blockIdx.x * 256 + threadIdx.x;
  if (i >= n4) return;
  float4 v = ((const float4*)s)[i];
  short4 o;
  o.x = f2bf(v.x); o.y = f2bf(v.y); o.z = f2bf(v.z); o.w = f2bf(v.w);
  ((short4*)d)[i] = o;
}

// -------- LayerNorm (optionally gathering tokens from x via idx) --------
template<bool GATHER>
__global__ __launch_bounds__(256) void k_ln(const float* __restrict__ x,
    const int* __restrict__ idx, float* __restrict__ hbuf,
    short* __restrict__ obf, const float* __restrict__ g,
    const float* __restrict__ beta) {
  __shared__ float red[8];
  int row = blockIdx.x;
  const float* src;
  if (GATHER) {
    int b = row >> 10, k = row & 1023;
    src = x + ((size_t)b*T_ + idx[b*S_ + k]) * C_;
  } else {
    src = hbuf + (size_t)row * C_;
  }
  int t = threadIdx.x;
  float4 v = *(const float4*)(src + t*4);
  float s  = v.x + v.y + v.z + v.w;
  float s2 = v.x*v.x + v.y*v.y + v.z*v.z + v.w*v.w;
  #pragma unroll
  for (int m = 32; m; m >>= 1) { s += __shfl_xor(s, m); s2 += __shfl_xor(s2, m); }
  int w = t >> 6, lane = t & 63;
  if (lane == 0) { red[w] = s; red[w+4] = s2; }
  __syncthreads();
  s  = red[0]+red[1]+red[2]+red[3];
  s2 = red[4]+red[5]+red[6]+red[7];
  float mu = s * (1.f/(float)C_);
  float var = s2 * (1.f/(float)C_) - mu*mu;
  float rs = rsqrtf(var + 1e-5f);
  int c0 = t*4;
  float4 gw = *(const float4*)(g + c0);
  float4 bw = *(const float4*)(beta + c0);
  short4 o;
  o.x = f2bf((v.x-mu)*rs*gw.x + bw.x);
  o.y = f2bf((v.y-mu)*rs*gw.y + bw.y);
  o.z = f2bf((v.z-mu)*rs*gw.z + bw.z);
  o.w = f2bf((v.w-mu)*rs*gw.w + bw.w);
  *(short4*)(obf + (size_t)row*C_ + c0) = o;
  if (GATHER) *(float4*)(hbuf + (size_t)row*C_ + c0) = v;
}

#define EPI_BF16 0
#define EPI_GELU 1
#define EPI_ADD32 2

__device__ __forceinline__ float gelu_exact(float v) {
  return 0.5f*v*(1.f + erff(v*0.70710678118654752f));
}

// ======== k_gemm4: m97-regime GEMM. 128xBN tile, BK=64, 256 thr, 32KB
// single-buffered LDS -> ~3 blocks/CU (cross-block TLP hides latency, m114).
// Conflict-free XOR swizzle (verified rounds 2-3), packed swapped epilogue. ====
template<int BM, int BN, int EPI, bool SKIPUP, bool CAUSK>
__global__ __launch_bounds__(256) void k_gemm4(
    const short* __restrict__ A, int lda,
    const short* __restrict__ Bp, int ldb,
    void* __restrict__ Cp, int ldc,
    const float* __restrict__ bias,
    int nNt, int Ktot, int zdiv,
    long long azo, long long azi, long long bzo, long long bzi,
    long long czo, long long czi) {
  constexpr int ACH = BM*64/8/256;   // A 16B-chunks per thread
  constexpr int BCH = BN*64/8/256;
  __shared__ short As[BM*64];
  __shared__ short Bs[BN*64];
  int z = blockIdx.z;
  int zo = z / zdiv, zi = z % zdiv;
  const short* Ab = A + zo*azo + zi*azi;
  const short* Bb = Bp + zo*bzo + zi*bzi;
  long long coff = zo*czo + zi*czi;
  // T1: bijective XCD swizzle (m204)
  int nwg = gridDim.x, orig = blockIdx.x;
  int q8 = nwg >> 3, r8 = nwg & 7;
  int xcd = orig & 7, loc = orig >> 3;
  int wg = (xcd < r8 ? xcd*(q8+1) : r8*(q8+1) + (xcd-r8)*q8) + loc;
  int bm = wg / nNt, bn = wg % nNt;
  if (SKIPUP && bn*BN > bm*BM + (BM-1)) return;   // tile fully above diagonal
  int kend = CAUSK ? (bm*BM + BM < Ktot ? bm*BM + BM : Ktot) : Ktot;
  const short* Ar = Ab + (size_t)bm*BM*lda;
  const short* Br = Bb + (size_t)bn*BN*ldb;
  constexpr int WM = BM/2, WN = BN/2, FM = WM/16, FN = WN/16;
  int t = threadIdx.x, lane = t & 63, w = t >> 6;
  int wm = w >> 1, wn = w & 1;
  int lr = lane & 15, kq = lane >> 4;
  f32x4 acc[FM][FN] = {};
  for (int k0 = 0; k0 < kend; k0 += 64) {
    // stage: row = ch>>3 (8x16B chunks per row = 128B contiguous, coalesced);
    // source chunk pre-permuted so linear LDS + XOR read is conflict-free.
    #pragma unroll
    for (int c = 0; c < ACH; ++c) {
      int ch = c*256 + t;
      int row = ch >> 3, sq = (ch & 7) ^ (row & 7);
      gload_lds16(Ar + (size_t)row*lda + (k0 + sq*8), &As[ch*8]);
    }
    #pragma unroll
    for (int c = 0; c < BCH; ++c) {
      int ch = c*256 + t;
      int row = ch >> 3, sq = (ch & 7) ^ (row & 7);
      gload_lds16(Br + (size_t)row*ldb + (k0 + sq*8), &Bs[ch*8]);
    }
    asm volatile("s_waitcnt vmcnt(0)" ::: "memory");
    __syncthreads();
    bf16x8 af[2][FM], bfv[2][FN];
    #pragma unroll
    for (int ks = 0; ks < 2; ++ks) {
      #pragma unroll
      for (int i = 0; i < FM; ++i) {
        int ra = wm*WM + i*16 + lr;
        af[ks][i] = *(const bf16x8*)&As[ra*64 + ((((ks<<2)+kq) ^ (ra & 7)) << 3)];
      }
      #pragma unroll
      for (int j = 0; j < FN; ++j) {
        int rb = wn*WN + j*16 + lr;
        bfv[ks][j] = *(const bf16x8*)&Bs[rb*64 + ((((ks<<2)+kq) ^ (rb & 7)) << 3)];
      }
    }
    #pragma unroll
    for (int ks = 0; ks < 2; ++ks)
      #pragma unroll
      for (int i = 0; i < FM; ++i)
        #pragma unroll
        for (int j = 0; j < FN; ++j)
          acc[i][j] = __builtin_amdgcn_mfma_f32_16x16x32_bf16(bfv[ks][j], af[ks][i], acc[i][j], 0, 0, 0);
    __syncthreads();
  }
  // packed swapped epilogue (verified rounds 2-3):
  // C[m = bm*BM + wm*WM + i*16 + (lane&15)][n = bn*BN + wn*WN + j*16 + kq*4 + r]
  int mrow0 = bm*BM + wm*WM + lr;
  int ncol0 = bn*BN + wn*WN + (kq << 2);
  #pragma unroll
  for (int i = 0; i < FM; ++i) {
    int row = mrow0 + i*16;
    #pragma unroll
    for (int j = 0; j < FN; ++j) {
      int col = ncol0 + j*16;
      float4 bv = bias ? *(const float4*)(bias + col) : make_float4(0.f,0.f,0.f,0.f);
      float v0 = acc[i][j][0] + bv.x, v1 = acc[i][j][1] + bv.y;
      float v2 = acc[i][j][2] + bv.z, v3 = acc[i][j][3] + bv.w;
      if (EPI == EPI_ADD32) {
        float* Co = (float*)Cp + coff + (size_t)row*ldc + col;
        float4 old = *(float4*)Co;
        old.x += v0; old.y += v1; old.z += v2; old.w += v3;
        *(float4*)Co = old;
      } else {
        if (EPI == EPI_GELU) {
          v0 = gelu_exact(v0); v1 = gelu_exact(v1);
          v2 = gelu_exact(v2); v3 = gelu_exact(v3);
        }
        short4 o; o.x = f2bf(v0); o.y = f2bf(v1); o.z = f2bf(v2); o.w = f2bf(v3);
        *(short4*)((short*)Cp + coff + (size_t)row*ldc + col) = o;
      }
    }
  }
}

// -------- V transpose: qkv[b,s,2C+h*64+d] -> vt[(b*H+h)*64+d][s] --------
__global__ __launch_bounds__(256) void k_vt(const short* __restrict__ qkv,
                                            short* __restrict__ vt) {
  __shared__ short tile[64][65];
  int blk = blockIdx.x;
  int s0 = (blk & 15) << 6;
  int bh = blk >> 4;
  int b = bh >> 4, h = bh & 15;
  const short* src = qkv + (size_t)b*S_*3*C_ + 2*C_ + h*DH_;
  int t = threadIdx.x;
  #pragma unroll
  for (int it = 0; it < 16; ++it) {
    int e = it*256 + t;
    int r = e >> 6, d = e & 63;
    tile[d][r] = src[(size_t)(s0 + r)*3*C_ + d];
  }
  __syncthreads();
  short* dst = vt + (size_t)bh*DH_*S_ + s0;
  #pragma unroll
  for (int it = 0; it < 16; ++it) {
    int e = it*256 + t;
    int d2 = e >> 6, c = e & 63;
    dst[(size_t)d2*S_ + c] = tile[d2][c];
  }
}

// -------- causal softmax, one block per row, vectorized bf16x4 I/O --------
__global__ __launch_bounds__(256) void k_softmax(short* __restrict__ sc) {
  __shared__ float red[4];
  int rowg = blockIdx.x;
  int q = rowg & (S_-1);
  short* p = sc + (size_t)rowg * S_;
  int t = threadIdx.x;
  short4 s4 = ((const short4*)p)[t];
  int c0 = t*4;
  float v[4] = { bf2f(s4.x)*0.125f, bf2f(s4.y)*0.125f,
                 bf2f(s4.z)*0.125f, bf2f(s4.w)*0.125f };
  float mx = -3.0e38f;
  #pragma unroll
  for (int i = 0; i < 4; ++i) {
    v[i] = (c0 + i <= q) ? v[i] : -3.0e38f;
    mx = fmaxf(mx, v[i]);
  }
  #pragma unroll
  for (int m = 32; m; m >>= 1) mx = fmaxf(mx, __shfl_xor(mx, m));
  int w = t >> 6, lane = t & 63;
  if (lane == 0) red[w] = mx;
  __syncthreads();
  mx = fmaxf(fmaxf(red[0], red[1]), fmaxf(red[2], red[3]));
  __syncthreads();
  float sum = 0.f;
  #pragma unroll
  for (int i = 0; i < 4; ++i) {
    v[i] = (v[i] > -1.0e38f) ? expf(v[i] - mx) : 0.f;
    sum += v[i];
  }
  #pragma unroll
  for (int m = 32; m; m >>= 1) sum += __shfl_xor(sum, m);
  if (lane == 0) red[w] = sum;
  __syncthreads();
  sum = red[0] + red[1] + red[2] + red[3];
  float inv = 1.f / sum;
  short4 o;
  o.x = f2bf(v[0]*inv); o.y = f2bf(v[1]*inv);
  o.z = f2bf(v[2]*inv); o.w = f2bf(v[3]*inv);
  ((short4*)p)[t] = o;
}

// -------- out = x everywhere --------
__global__ void k_copy(const float* __restrict__ src, float* __restrict__ dst,
                       size_t n4) {
  size_t i = (size_t)blockIdx.x*256 + threadIdx.x;
  size_t stride = (size_t)gridDim.x*256;
  for (; i < n4; i += stride) ((float4*)dst)[i] = ((const float4*)src)[i];
}

// -------- out[selected row] = x + weight * h --------
__global__ __launch_bounds__(256) void k_scatter(const float* __restrict__ x,
    const int* __restrict__ idx, const float* __restrict__ wts,
    const float* __restrict__ hbuf, float* __restrict__ out) {
  int row = blockIdx.x;
  int b = row >> 10, k = row & 1023;
  int tk = idx[(size_t)b*S_ + k];
  float wv = wts[(size_t)b*S_ + k];
  size_t o  = ((size_t)b*T_ + tk)*C_ + threadIdx.x*4;
  size_t hs = (size_t)row*C_ + threadIdx.x*4;
  float4 xv = *(const float4*)(x + o);
  float4 hv = *(const float4*)(hbuf + hs);
  xv.x += wv*hv.x; xv.y += wv*hv.y; xv.z += wv*hv.z; xv.w += wv*hv.w;
  *(float4*)(out + o) = xv;
}

extern "C" void kernel_launch(void* const* d_in, const int* in_sizes, int n_in,
                              void* d_out, int out_size, void* d_ws, size_t ws_size,
                              hipStream_t stream) {
  const float* x     = (const float*)d_in[0];
  const float* wrt   = (const float*)d_in[1];
  const float* ln1w  = (const float*)d_in[2];
  const float* ln1b  = (const float*)d_in[3];
  const float* wqkv  = (const float*)d_in[4];
  const float* bqkv  = (const float*)d_in[5];
  const float* wo    = (const float*)d_in[6];
  const float* bo    = (const float*)d_in[7];
  const float* ln2w  = (const float*)d_in[8];
  const float* ln2b  = (const float*)d_in[9];
  const float* wfc   = (const float*)d_in[10];
  const float* bfc   = (const float*)d_in[11];
  const float* wproj = (const float*)d_in[12];
  const float* bproj = (const float*)d_in[13];
  float* out = (float*)d_out;

  char* p = (char*)d_ws;
  auto alloc = [&](size_t bytes) {
    char* r = p; p += (bytes + 255) & ~(size_t)255; return r;
  };
  float* logits = (float*)alloc((size_t)B_*T_*4);
  int*   idx    = (int*)  alloc((size_t)B_*S_*4);
  float* wts    = (float*)alloc((size_t)B_*S_*4);
  float* hbuf   = (float*)alloc((size_t)M_*C_*4);
  short* abuf   = (short*)alloc((size_t)M_*C_*2);
  short* qkvb   = (short*)alloc((size_t)M_*3*C_*2);
  short* vtb    = (short*)alloc((size_t)B_*H_*DH_*S_*2);
  short* attnb  = (short*)alloc((size_t)M_*C_*2);
  short* fcb    = (short*)alloc((size_t)M_*DFF_*2);
  short* wqkvb  = (short*)alloc((size_t)3*C_*C_*2);
  short* wob    = (short*)alloc((size_t)C_*C_*2);
  short* wfcb   = (short*)alloc((size_t)DFF_*C_*2);
  short* wprojb = (short*)alloc((size_t)C_*DFF_*2);
  short* scb = fcb;
  if (ws_size < (size_t)(p - (char*)d_ws)) return;

  k_cvt<<<dim3(3*C_*C_/4/256), dim3(256), 0, stream>>>(wqkv, wqkvb, 3*C_*C_/4);
  k_cvt<<<dim3(C_*C_/4/256),   dim3(256), 0, stream>>>(wo, wob, C_*C_/4);
  k_cvt<<<dim3(DFF_*C_/4/256), dim3(256), 0, stream>>>(wfc, wfcb, DFF_*C_/4);
  k_cvt<<<dim3(C_*DFF_/4/256), dim3(256), 0, stream>>>(wproj, wprojb, C_*DFF_/4);

  k_router<<<dim3(B_*T_/4), dim3(256), 0, stream>>>(x, wrt, logits);
  k_topk<<<dim3(B_), dim3(1024), 0, stream>>>(logits, idx, wts);

  k_ln<true><<<dim3(M_), dim3(256), 0, stream>>>(x, idx, hbuf, abuf, ln1w, ln1b);

  // QKV: [8192,1024] @ [3072,1024]^T
  k_gemm4<128,128,EPI_BF16,false,false>
    <<<dim3((M_/128)*(3*C_/128), 1, 1), dim3(256), 0, stream>>>(
      abuf, C_, wqkvb, C_, qkvb, 3*C_, bqkv, 3*C_/128, C_, 1, 0,0,0,0,0,0);

  k_vt<<<dim3(B_*H_*(S_/64)), dim3(256), 0, stream>>>(qkvb, vtb);

  for (int b0 = 0; b0 < B_; b0 += CHUNKB) {
    // scores = Q @ K^T (tiles above diagonal skipped); K=64 -> single K-tile
    k_gemm4<128,128,EPI_BF16,true,false>
      <<<dim3((S_/128)*(S_/128), 1, CHUNKB*H_), dim3(256), 0, stream>>>(
        qkvb + (size_t)b0*S_*3*C_, 3*C_,
        qkvb + (size_t)b0*S_*3*C_ + C_, 3*C_,
        scb, S_, nullptr, S_/128, DH_, H_,
        (long long)S_*3*C_, (long long)DH_,
        (long long)S_*3*C_, (long long)DH_,
        (long long)H_*S_*S_, (long long)S_*S_);
    k_softmax<<<dim3(CHUNKB*H_*S_), dim3(256), 0, stream>>>(scb);
    // attn = P @ V  (causal K truncation)
    k_gemm4<128,64,EPI_BF16,false,true>
      <<<dim3((S_/128)*(DH_/64), 1, CHUNKB*H_), dim3(256), 0, stream>>>(
        scb, S_,
        vtb + (size_t)b0*H_*DH_*S_, S_,
        attnb + (size_t)b0*S_*C_, C_, nullptr, DH_/64, S_, H_,
        (long long)H_*S_*S_, (long long)S_*S_,
        (long long)H_*DH_*S_, (long long)DH_*S_,
        (long long)S_*C_, (long long)DH_);
  }

  // h += attn @ w_o^T + b_o
  k_gemm4<128,128,EPI_ADD32,false,false>
    <<<dim3((M_/128)*(C_/128), 1, 1), dim3(256), 0, stream>>>(
      attnb, C_, wob, C_, hbuf, C_, bo, C_/128, C_, 1, 0,0,0,0,0,0);

  k_ln<false><<<dim3(M_), dim3(256), 0, stream>>>(nullptr, nullptr, hbuf, abuf, ln2w, ln2b);

  // fc = gelu(m @ w_fc^T + b_fc)
  k_gemm4<128,128,EPI_GELU,false,false>
    <<<dim3((M_/128)*(DFF_/128), 1, 1), dim3(256), 0, stream>>>(
      abuf, C_, wfcb, C_, fcb, DFF_, bfc, DFF_/128, C_, 1, 0,0,0,0,0,0);

  // h += fc @ w_proj^T + b_proj
  k_gemm4<128,128,EPI_ADD32,false,false>
    <<<dim3((M_/128)*(C_/128), 1, 1), dim3(256), 0, stream>>>(
      fcb, DFF_, wprojb, DFF_, hbuf, C_, bproj, C_/128, DFF_, 1, 0,0,0,0,0,0);

  k_copy<<<dim3(2048), dim3(256), 0, stream>>>(x, out, (size_t)B_*T_*C_/4);
  k_scatter<<<dim3(M_), dim3(256), 0, stream>>>(x, idx, wts, hbuf, out);
}

// Round 6
// 560.486 us; speedup vs baseline: 1.4542x; 1.4034x over previous
//
#include <hip/hip_runtime.h>
#include <hip/hip_bf16.h>

#define B_ 8
#define T_ 2048
#define C_ 1024
#define S_ 1024      // top_k == reduced sequence length
#define H_ 16
#define DH_ 64
#define DFF_ 4096
#define M_ (B_*S_)   // 8192 rows through the block

typedef __attribute__((ext_vector_type(8))) short bf16x8;
typedef __attribute__((ext_vector_type(4))) float f32x4;

__device__ __forceinline__ short f2bf(float f) {
  __hip_bfloat16 h = __float2bfloat16(f);
  return *reinterpret_cast<short*>(&h);
}
__device__ __forceinline__ float bf2f(short s) {
  __hip_bfloat16 h = *reinterpret_cast<__hip_bfloat16*>(&s);
  return __bfloat162float(h);
}

typedef const __attribute__((address_space(1))) unsigned int* gas_p;
typedef __attribute__((address_space(3))) unsigned int* las_p;
__device__ __forceinline__ void gload_lds16(const void* g, void* l) {
  __builtin_amdgcn_global_load_lds((gas_p)g, (las_p)l, 16, 0, 0);
}

// ---------------- router logits: one wave per token ----------------
__global__ __launch_bounds__(256) void k_router(const float* __restrict__ x,
    const float* __restrict__ wr, float* __restrict__ logits) {
  int tok = blockIdx.x * 4 + (threadIdx.x >> 6);
  int l = threadIdx.x & 63;
  const float* xr = x + (size_t)tok * C_;
  float s = 0.f;
  #pragma unroll
  for (int j = 0; j < C_/64; ++j) s += xr[l + 64*j] * wr[l + 64*j];
  #pragma unroll
  for (int m = 32; m; m >>= 1) s += __shfl_xor(s, m);
  if (l == 0) logits[tok] = s;
}

// ------------- exact top-k via bitonic sort (1 block / batch) -------------
__global__ __launch_bounds__(1024) void k_topk(const float* __restrict__ logits,
    int* __restrict__ idx, float* __restrict__ wts) {
  __shared__ unsigned long long key[2048];
  int b = blockIdx.x, t = threadIdx.x;
  for (int i = t; i < T_; i += 1024) {
    float v = logits[(size_t)b*T_ + i];
    unsigned u = __float_as_uint(v);
    unsigned so = u ^ ((u >> 31) ? 0xFFFFFFFFu : 0x80000000u);
    key[i] = ((unsigned long long)(~so) << 32) | (unsigned)i;
  }
  __syncthreads();
  for (int k = 2; k <= 2048; k <<= 1) {
    for (int j = k >> 1; j > 0; j >>= 1) {
      int i = ((t & ~(j-1)) << 1) | (t & (j-1));
      int ix = i | j;
      unsigned long long a = key[i], c = key[ix];
      bool up = ((i & k) == 0);
      if ((a > c) == up) { key[i] = c; key[ix] = a; }
      __syncthreads();
    }
  }
  unsigned long long a = key[t];
  __syncthreads();
  unsigned i0 = (unsigned)(a & 0xFFFFFFFFu);
  unsigned so = ~(unsigned)(a >> 32);
  unsigned bits = (so & 0x80000000u) ? (so ^ 0x80000000u) : ~so;
  key[t] = ((unsigned long long)i0 << 32) | bits;
  __syncthreads();
  for (int k = 2; k <= 1024; k <<= 1) {
    for (int j = k >> 1; j > 0; j >>= 1) {
      if (t < 512) {
        int i = ((t & ~(j-1)) << 1) | (t & (j-1));
        int ix = i | j;
        unsigned long long a2 = key[i], c2 = key[ix];
        bool up = ((i & k) == 0);
        if ((a2 > c2) == up) { key[i] = c2; key[ix] = a2; }
      }
      __syncthreads();
    }
  }
  idx[(size_t)b*S_ + t] = (int)(key[t] >> 32);
  wts[(size_t)b*S_ + t] = __uint_as_float((unsigned)(key[t] & 0xFFFFFFFFu));
}

// -------- fp32 -> bf16 conversion (weights) --------
__global__ __launch_bounds__(256) void k_cvt(const float* __restrict__ s,
    short* __restrict__ d, int n4) {
  int i = blockIdx.x * 256 + threadIdx.x;
  if (i >= n4) return;
  float4 v = ((const float4*)s)[i];
  short4 o;
  o.x = f2bf(v.x); o.y = f2bf(v.y); o.z = f2bf(v.z); o.w = f2bf(v.w);
  ((short4*)d)[i] = o;
}

// -------- LayerNorm (optionally gathering tokens from x via idx) --------
template<bool GATHER>
__global__ __launch_bounds__(256) void k_ln(const float* __restrict__ x,
    const int* __restrict__ idx, float* __restrict__ hbuf,
    short* __restrict__ obf, const float* __restrict__ g,
    const float* __restrict__ beta) {
  __shared__ float red[8];
  int row = blockIdx.x;
  const float* src;
  if (GATHER) {
    int b = row >> 10, k = row & 1023;
    src = x + ((size_t)b*T_ + idx[b*S_ + k]) * C_;
  } else {
    src = hbuf + (size_t)row * C_;
  }
  int t = threadIdx.x;
  float4 v = *(const float4*)(src + t*4);
  float s  = v.x + v.y + v.z + v.w;
  float s2 = v.x*v.x + v.y*v.y + v.z*v.z + v.w*v.w;
  #pragma unroll
  for (int m = 32; m; m >>= 1) { s += __shfl_xor(s, m); s2 += __shfl_xor(s2, m); }
  int w = t >> 6, lane = t & 63;
  if (lane == 0) { red[w] = s; red[w+4] = s2; }
  __syncthreads();
  s  = red[0]+red[1]+red[2]+red[3];
  s2 = red[4]+red[5]+red[6]+red[7];
  float mu = s * (1.f/(float)C_);
  float var = s2 * (1.f/(float)C_) - mu*mu;
  float rs = rsqrtf(var + 1e-5f);
  int c0 = t*4;
  float4 gw = *(const float4*)(g + c0);
  float4 bw = *(const float4*)(beta + c0);
  short4 o;
  o.x = f2bf((v.x-mu)*rs*gw.x + bw.x);
  o.y = f2bf((v.y-mu)*rs*gw.y + bw.y);
  o.z = f2bf((v.z-mu)*rs*gw.z + bw.z);
  o.w = f2bf((v.w-mu)*rs*gw.w + bw.w);
  *(short4*)(obf + (size_t)row*C_ + c0) = o;
  if (GATHER) *(float4*)(hbuf + (size_t)row*C_ + c0) = v;
}

#define EPI_BF16 0
#define EPI_GELU 1
#define EPI_ADD32 2

// branch-free tanh-form GELU (|err| <= ~4e-4): ~8 VALU ops, no erff
__device__ __forceinline__ float gelu_fast(float v) {
  float z = 0.7978845608f * (v + 0.044715f * v * v * v);
  float e = __expf(2.f * z);
  return v - v * __builtin_amdgcn_rcpf(e + 1.f);
}

// ======== k_gemm4: m97-regime GEMM (unchanged structure from round 4) ========
template<int BM, int BN, int EPI>
__global__ __launch_bounds__(256) void k_gemm4(
    const short* __restrict__ A, int lda,
    const short* __restrict__ Bp, int ldb,
    void* __restrict__ Cp, int ldc,
    const float* __restrict__ bias,
    int nNt, int Ktot) {
  constexpr int ACH = BM*64/8/256;
  constexpr int BCH = BN*64/8/256;
  __shared__ short As[BM*64];
  __shared__ short Bs[BN*64];
  // T1: bijective XCD swizzle (m204)
  int nwg = gridDim.x, orig = blockIdx.x;
  int q8 = nwg >> 3, r8 = nwg & 7;
  int xcd = orig & 7, loc = orig >> 3;
  int wg = (xcd < r8 ? xcd*(q8+1) : r8*(q8+1) + (xcd-r8)*q8) + loc;
  int bm = wg / nNt, bn = wg % nNt;
  const short* Ar = A + (size_t)bm*BM*lda;
  const short* Br = Bp + (size_t)bn*BN*ldb;
  constexpr int WM = BM/2, WN = BN/2, FM = WM/16, FN = WN/16;
  int t = threadIdx.x, lane = t & 63, w = t >> 6;
  int wm = w >> 1, wn = w & 1;
  int lr = lane & 15, kq = lane >> 4;
  f32x4 acc[FM][FN] = {};
  for (int k0 = 0; k0 < Ktot; k0 += 64) {
    #pragma unroll
    for (int c = 0; c < ACH; ++c) {
      int ch = c*256 + t;
      int row = ch >> 3, sq = (ch & 7) ^ (row & 7);
      gload_lds16(Ar + (size_t)row*lda + (k0 + sq*8), &As[ch*8]);
    }
    #pragma unroll
    for (int c = 0; c < BCH; ++c) {
      int ch = c*256 + t;
      int row = ch >> 3, sq = (ch & 7) ^ (row & 7);
      gload_lds16(Br + (size_t)row*ldb + (k0 + sq*8), &Bs[ch*8]);
    }
    asm volatile("s_waitcnt vmcnt(0)" ::: "memory");
    __syncthreads();
    bf16x8 af[2][FM], bfv[2][FN];
    #pragma unroll
    for (int ks = 0; ks < 2; ++ks) {
      #pragma unroll
      for (int i = 0; i < FM; ++i) {
        int ra = wm*WM + i*16 + lr;
        af[ks][i] = *(const bf16x8*)&As[ra*64 + ((((ks<<2)+kq) ^ (ra & 7)) << 3)];
      }
      #pragma unroll
      for (int j = 0; j < FN; ++j) {
        int rb = wn*WN + j*16 + lr;
        bfv[ks][j] = *(const bf16x8*)&Bs[rb*64 + ((((ks<<2)+kq) ^ (rb & 7)) << 3)];
      }
    }
    #pragma unroll
    for (int ks = 0; ks < 2; ++ks)
      #pragma unroll
      for (int i = 0; i < FM; ++i)
        #pragma unroll
        for (int j = 0; j < FN; ++j)
          acc[i][j] = __builtin_amdgcn_mfma_f32_16x16x32_bf16(bfv[ks][j], af[ks][i], acc[i][j], 0, 0, 0);
    __syncthreads();
  }
  int mrow0 = bm*BM + wm*WM + lr;
  int ncol0 = bn*BN + wn*WN + (kq << 2);
  #pragma unroll
  for (int i = 0; i < FM; ++i) {
    int row = mrow0 + i*16;
    #pragma unroll
    for (int j = 0; j < FN; ++j) {
      int col = ncol0 + j*16;
      float4 bv = bias ? *(const float4*)(bias + col) : make_float4(0.f,0.f,0.f,0.f);
      float v0 = acc[i][j][0] + bv.x, v1 = acc[i][j][1] + bv.y;
      float v2 = acc[i][j][2] + bv.z, v3 = acc[i][j][3] + bv.w;
      if (EPI == EPI_ADD32) {
        float* Co = (float*)Cp + (size_t)row*ldc + col;
        float4 old = *(float4*)Co;
        old.x += v0; old.y += v1; old.z += v2; old.w += v3;
        *(float4*)Co = old;
      } else {
        if (EPI == EPI_GELU) {
          v0 = gelu_fast(v0); v1 = gelu_fast(v1);
          v2 = gelu_fast(v2); v3 = gelu_fast(v3);
        }
        short4 o; o.x = f2bf(v0); o.y = f2bf(v1); o.z = f2bf(v2); o.w = f2bf(v3);
        *(short4*)((short*)Cp + (size_t)row*ldc + col) = o;
      }
    }
  }
}

// -------- V transpose: qkv[b,s,2C+h*64+d] -> vt[(b*H+h)*64+d][s] --------
__global__ __launch_bounds__(256) void k_vt(const short* __restrict__ qkv,
                                            short* __restrict__ vt) {
  __shared__ short tile[64][65];
  int blk = blockIdx.x;
  int s0 = (blk & 15) << 6;
  int bh = blk >> 4;
  int b = bh >> 4, h = bh & 15;
  const short* src = qkv + (size_t)b*S_*3*C_ + 2*C_ + h*DH_;
  int t = threadIdx.x;
  #pragma unroll
  for (int it = 0; it < 16; ++it) {
    int e = it*256 + t;
    int r = e >> 6, d = e & 63;
    tile[d][r] = src[(size_t)(s0 + r)*3*C_ + d];
  }
  __syncthreads();
  short* dst = vt + (size_t)bh*DH_*S_ + s0;
  #pragma unroll
  for (int it = 0; it < 16; ++it) {
    int e = it*256 + t;
    int d2 = e >> 6, c = e & 63;
    dst[(size_t)d2*S_ + c] = tile[d2][c];
  }
}

// ======== k_fattn: fused causal flash attention ========
// One block per (128 q-rows, head). 4 waves x 32 q-rows each.
// acc layout (verified): acc[i][j][r] = C[m=16i+lr][n=16j+4kq+r], C=Y@X^T for
// mfma(X_frag, Y_frag, acc). Online softmax rows are lane-local per (i,lr),
// reduced across the 4 kq-lanes via shfl_xor 16/32. P relayout via per-wave
// padded LDS slice (write acc-layout, read A-frag layout), barrier-guarded.
__global__ __launch_bounds__(256) void k_fattn(
    const short* __restrict__ qkv, const short* __restrict__ vt,
    short* __restrict__ attnb) {
  __shared__ short Ks[128*64];       // K tile (also Q staging) 16KB
  __shared__ short Vs[64*128];       // V^T tile 16KB
  __shared__ short Ps[4][32*136];    // per-wave P slice, +8 pad  ~34KB
  int qt = blockIdx.x;               // 0..7
  int bh = blockIdx.y;               // b*16+h
  int b = bh >> 4, h = bh & 15;
  int t = threadIdx.x, lane = t & 63, w = t >> 6;
  int lr = lane & 15, kq = lane >> 4;
  const short* Qbase = qkv + ((size_t)b*S_ + qt*128)*3*C_ + h*DH_;
  const short* Kbase = qkv + (size_t)b*S_*3*C_ + C_ + h*DH_;
  const short* Vtb   = vt + (size_t)bh*DH_*S_;

  // ---- stage Q tile into Ks, read Q frags to regs, release Ks ----
  #pragma unroll
  for (int c = 0; c < 4; ++c) {
    int ch = c*256 + t;
    int row = ch >> 3, sq = (ch & 7) ^ (row & 7);
    gload_lds16(Qbase + (size_t)row*3*C_ + sq*8, &Ks[ch*8]);
  }
  asm volatile("s_waitcnt vmcnt(0)" ::: "memory");
  __syncthreads();
  bf16x8 qf[2][2];
  #pragma unroll
  for (int ks = 0; ks < 2; ++ks)
    #pragma unroll
    for (int i = 0; i < 2; ++i) {
      int rq = w*32 + i*16 + lr;
      qf[ks][i] = *(const bf16x8*)&Ks[rq*64 + ((((ks<<2)+kq) ^ (rq & 7)) << 3)];
    }
  __syncthreads();

  f32x4 o[2][4] = {};
  float m_i[2] = {-3.0e38f, -3.0e38f};
  float l_i[2] = {0.f, 0.f};
  short* Pw = &Ps[w][0];

  for (int j128 = 0; j128 <= qt; ++j128) {
    // stage K_j [128 x 64] and V^T_j [64 x 128]
    #pragma unroll
    for (int c = 0; c < 4; ++c) {
      int ch = c*256 + t;
      int row = ch >> 3, sq = (ch & 7) ^ (row & 7);
      gload_lds16(Kbase + (size_t)(j128*128 + row)*3*C_ + sq*8, &Ks[ch*8]);
    }
    #pragma unroll
    for (int c = 0; c < 4; ++c) {
      int ch = c*256 + t;
      int row = ch >> 4, cc = ch & 15, sq = cc ^ ((row & 7) << 1);
      gload_lds16(Vtb + (size_t)row*S_ + (j128*128 + sq*8), &Vs[ch*8]);
    }
    asm volatile("s_waitcnt vmcnt(0)" ::: "memory");
    __syncthreads();

    // S = Q @ K^T for this wave's 32 q-rows x 128 kv
    f32x4 s[2][8] = {};
    #pragma unroll
    for (int ks = 0; ks < 2; ++ks) {
      bf16x8 kf[8];
      #pragma unroll
      for (int j = 0; j < 8; ++j) {
        int rk = j*16 + lr;
        kf[j] = *(const bf16x8*)&Ks[rk*64 + ((((ks<<2)+kq) ^ (rk & 7)) << 3)];
      }
      #pragma unroll
      for (int i = 0; i < 2; ++i)
        #pragma unroll
        for (int j = 0; j < 8; ++j)
          s[i][j] = __builtin_amdgcn_mfma_f32_16x16x32_bf16(kf[j], qf[ks][i], s[i][j], 0, 0, 0);
    }

    // online softmax
    bool diag = (j128 == qt);
    #pragma unroll
    for (int i = 0; i < 2; ++i) {
      int qrow = w*32 + i*16 + lr;     // block-local; same window as kv on diag
      float rmax = -3.0e38f;
      #pragma unroll
      for (int j = 0; j < 8; ++j)
        #pragma unroll
        for (int r = 0; r < 4; ++r) {
          int col = j*16 + (kq<<2) + r;
          float v = s[i][j][r] * 0.125f;
          if (diag && col > qrow) v = -3.0e38f;
          s[i][j][r] = v;
          rmax = fmaxf(rmax, v);
        }
      rmax = fmaxf(rmax, __shfl_xor(rmax, 16));
      rmax = fmaxf(rmax, __shfl_xor(rmax, 32));
      float mnew = fmaxf(m_i[i], rmax);
      float alpha = __expf(m_i[i] - mnew);
      m_i[i] = mnew;
      float rsum = 0.f;
      #pragma unroll
      for (int j = 0; j < 8; ++j)
        #pragma unroll
        for (int r = 0; r < 4; ++r) {
          float p = __expf(s[i][j][r] - mnew);
          s[i][j][r] = p;
          rsum += p;
        }
      rsum += __shfl_xor(rsum, 16);
      rsum += __shfl_xor(rsum, 32);
      l_i[i] = l_i[i]*alpha + rsum;
      #pragma unroll
      for (int jo = 0; jo < 4; ++jo)
        #pragma unroll
        for (int r = 0; r < 4; ++r)
          o[i][jo][r] *= alpha;
    }

    // P (acc layout) -> per-wave LDS slice (bf16)
    #pragma unroll
    for (int i = 0; i < 2; ++i)
      #pragma unroll
      for (int j = 0; j < 8; ++j) {
        short4 pk;
        pk.x = f2bf(s[i][j][0]); pk.y = f2bf(s[i][j][1]);
        pk.z = f2bf(s[i][j][2]); pk.w = f2bf(s[i][j][3]);
        int prow = i*16 + lr;
        *(short4*)&Pw[prow*136 + j*16 + (kq<<2)] = pk;
      }
    __syncthreads();   // P visible (in-wave exchange; barrier removes all doubt)

    // O += P @ V  : af = P rows (this wave), bfv = V^T rows d
    #pragma unroll
    for (int sstep = 0; sstep < 4; ++sstep) {
      bf16x8 pf[2], vf[4];
      #pragma unroll
      for (int i = 0; i < 2; ++i) {
        int prow = i*16 + lr;
        pf[i] = *(const bf16x8*)&Pw[prow*136 + sstep*32 + (kq<<3)];
      }
      #pragma unroll
      for (int jo = 0; jo < 4; ++jo) {
        int rv = jo*16 + lr;
        int cc = (sstep*4 + kq) ^ ((rv & 7) << 1);
        vf[jo] = *(const bf16x8*)&Vs[rv*128 + cc*8];
      }
      #pragma unroll
      for (int i = 0; i < 2; ++i)
        #pragma unroll
        for (int jo = 0; jo < 4; ++jo)
          o[i][jo] = __builtin_amdgcn_mfma_f32_16x16x32_bf16(vf[jo], pf[i], o[i][jo], 0, 0, 0);
    }
    __syncthreads();   // before next stage overwrites Ks/Vs
  }

  // epilogue: attn[b, q, h*64+d] = O / l
  #pragma unroll
  for (int i = 0; i < 2; ++i) {
    float inv = 1.f / l_i[i];
    int q = qt*128 + w*32 + i*16 + lr;
    #pragma unroll
    for (int jo = 0; jo < 4; ++jo) {
      int d = jo*16 + (kq<<2);
      short4 ov;
      ov.x = f2bf(o[i][jo][0]*inv); ov.y = f2bf(o[i][jo][1]*inv);
      ov.z = f2bf(o[i][jo][2]*inv); ov.w = f2bf(o[i][jo][3]*inv);
      *(short4*)&attnb[((size_t)b*S_ + q)*C_ + h*DH_ + d] = ov;
    }
  }
}

// -------- out = x everywhere --------
__global__ void k_copy(const float* __restrict__ src, float* __restrict__ dst,
                       size_t n4) {
  size_t i = (size_t)blockIdx.x*256 + threadIdx.x;
  size_t stride = (size_t)gridDim.x*256;
  for (; i < n4; i += stride) ((float4*)dst)[i] = ((const float4*)src)[i];
}

// -------- out[selected row] = x + weight * h --------
__global__ __launch_bounds__(256) void k_scatter(const float* __restrict__ x,
    const int* __restrict__ idx, const float* __restrict__ wts,
    const float* __restrict__ hbuf, float* __restrict__ out) {
  int row = blockIdx.x;
  int b = row >> 10, k = row & 1023;
  int tk = idx[(size_t)b*S_ + k];
  float wv = wts[(size_t)b*S_ + k];
  size_t o  = ((size_t)b*T_ + tk)*C_ + threadIdx.x*4;
  size_t hs = (size_t)row*C_ + threadIdx.x*4;
  float4 xv = *(const float4*)(x + o);
  float4 hv = *(const float4*)(hbuf + hs);
  xv.x += wv*hv.x; xv.y += wv*hv.y; xv.z += wv*hv.z; xv.w += wv*hv.w;
  *(float4*)(out + o) = xv;
}

extern "C" void kernel_launch(void* const* d_in, const int* in_sizes, int n_in,
                              void* d_out, int out_size, void* d_ws, size_t ws_size,
                              hipStream_t stream) {
  const float* x     = (const float*)d_in[0];
  const float* wrt   = (const float*)d_in[1];
  const float* ln1w  = (const float*)d_in[2];
  const float* ln1b  = (const float*)d_in[3];
  const float* wqkv  = (const float*)d_in[4];
  const float* bqkv  = (const float*)d_in[5];
  const float* wo    = (const float*)d_in[6];
  const float* bo    = (const float*)d_in[7];
  const float* ln2w  = (const float*)d_in[8];
  const float* ln2b  = (const float*)d_in[9];
  const float* wfc   = (const float*)d_in[10];
  const float* bfc   = (const float*)d_in[11];
  const float* wproj = (const float*)d_in[12];
  const float* bproj = (const float*)d_in[13];
  float* out = (float*)d_out;

  char* p = (char*)d_ws;
  auto alloc = [&](size_t bytes) {
    char* r = p; p += (bytes + 255) & ~(size_t)255; return r;
  };
  float* logits = (float*)alloc((size_t)B_*T_*4);
  int*   idx    = (int*)  alloc((size_t)B_*S_*4);
  float* wts    = (float*)alloc((size_t)B_*S_*4);
  float* hbuf   = (float*)alloc((size_t)M_*C_*4);
  short* abuf   = (short*)alloc((size_t)M_*C_*2);
  short* qkvb   = (short*)alloc((size_t)M_*3*C_*2);
  short* vtb    = (short*)alloc((size_t)B_*H_*DH_*S_*2);
  short* attnb  = (short*)alloc((size_t)M_*C_*2);
  short* fcb    = (short*)alloc((size_t)M_*DFF_*2);
  short* wqkvb  = (short*)alloc((size_t)3*C_*C_*2);
  short* wob    = (short*)alloc((size_t)C_*C_*2);
  short* wfcb   = (short*)alloc((size_t)DFF_*C_*2);
  short* wprojb = (short*)alloc((size_t)C_*DFF_*2);
  if (ws_size < (size_t)(p - (char*)d_ws)) return;

  k_cvt<<<dim3(3*C_*C_/4/256), dim3(256), 0, stream>>>(wqkv, wqkvb, 3*C_*C_/4);
  k_cvt<<<dim3(C_*C_/4/256),   dim3(256), 0, stream>>>(wo, wob, C_*C_/4);
  k_cvt<<<dim3(DFF_*C_/4/256), dim3(256), 0, stream>>>(wfc, wfcb, DFF_*C_/4);
  k_cvt<<<dim3(C_*DFF_/4/256), dim3(256), 0, stream>>>(wproj, wprojb, C_*DFF_/4);

  k_router<<<dim3(B_*T_/4), dim3(256), 0, stream>>>(x, wrt, logits);
  k_topk<<<dim3(B_), dim3(1024), 0, stream>>>(logits, idx, wts);

  k_ln<true><<<dim3(M_), dim3(256), 0, stream>>>(x, idx, hbuf, abuf, ln1w, ln1b);

  // QKV: [8192,1024] @ [3072,1024]^T
  k_gemm4<128,128,EPI_BF16>
    <<<dim3((M_/128)*(3*C_/128)), dim3(256), 0, stream>>>(
      abuf, C_, wqkvb, C_, qkvb, 3*C_, bqkv, 3*C_/128, C_);

  k_vt<<<dim3(B_*H_*(S_/64)), dim3(256), 0, stream>>>(qkvb, vtb);

  // fused causal flash attention
  k_fattn<<<dim3(S_/128, B_*H_), dim3(256), 0, stream>>>(qkvb, vtb, attnb);

  // h += attn @ w_o^T + b_o
  k_gemm4<128,128,EPI_ADD32>
    <<<dim3((M_/128)*(C_/128)), dim3(256), 0, stream>>>(
      attnb, C_, wob, C_, hbuf, C_, bo, C_/128, C_);

  k_ln<false><<<dim3(M_), dim3(256), 0, stream>>>(nullptr, nullptr, hbuf, abuf, ln2w, ln2b);

  // fc = gelu(m @ w_fc^T + b_fc)
  k_gemm4<128,128,EPI_GELU>
    <<<dim3((M_/128)*(DFF_/128)), dim3(256), 0, stream>>>(
      abuf, C_, wfcb, C_, fcb, DFF_, bfc, DFF_/128, C_);

  // h += fc @ w_proj^T + b_proj
  k_gemm4<128,128,EPI_ADD32>
    <<<dim3((M_/128)*(C_/128)), dim3(256), 0, stream>>>(
      fcb, DFF_, wprojb, DFF_, hbuf, C_, bproj, C_/128, DFF_);

  k_copy<<<dim3(2048), dim3(256), 0, stream>>>(x, out, (size_t)B_*T_*C_/4);
  k_scatter<<<dim3(M_), dim3(256), 0, stream>>>(x, idx, wts, hbuf, out);
}

// Round 7
// 533.543 us; speedup vs baseline: 1.5277x; 1.0505x over previous
//
#include <hip/hip_runtime.h>
#include <hip/hip_bf16.h>

#define B_ 8
#define T_ 2048
#define C_ 1024
#define S_ 1024      // top_k == reduced sequence length
#define H_ 16
#define DH_ 64
#define DFF_ 4096
#define M_ (B_*S_)   // 8192 rows through the block

typedef __attribute__((ext_vector_type(8))) short bf16x8;
typedef __attribute__((ext_vector_type(4))) float f32x4;

__device__ __forceinline__ short f2bf(float f) {
  __hip_bfloat16 h = __float2bfloat16(f);
  return *reinterpret_cast<short*>(&h);
}
__device__ __forceinline__ float bf2f(short s) {
  __hip_bfloat16 h = *reinterpret_cast<__hip_bfloat16*>(&s);
  return __bfloat162float(h);
}

typedef const __attribute__((address_space(1))) unsigned int* gas_p;
typedef __attribute__((address_space(3))) unsigned int* las_p;
__device__ __forceinline__ void gload_lds16(const void* g, void* l) {
  __builtin_amdgcn_global_load_lds((gas_p)g, (las_p)l, 16, 0, 0);
}

// ---------------- router logits: one wave per token ----------------
__global__ __launch_bounds__(256) void k_router(const float* __restrict__ x,
    const float* __restrict__ wr, float* __restrict__ logits) {
  int tok = blockIdx.x * 4 + (threadIdx.x >> 6);
  int l = threadIdx.x & 63;
  const float* xr = x + (size_t)tok * C_;
  float s = 0.f;
  #pragma unroll
  for (int j = 0; j < C_/64; ++j) s += xr[l + 64*j] * wr[l + 64*j];
  #pragma unroll
  for (int m = 32; m; m >>= 1) s += __shfl_xor(s, m);
  if (l == 0) logits[tok] = s;
}

// ------------- exact top-k via bitonic sort (1 block / batch) -------------
__global__ __launch_bounds__(1024) void k_topk(const float* __restrict__ logits,
    int* __restrict__ idx, float* __restrict__ wts) {
  __shared__ unsigned long long key[2048];
  int b = blockIdx.x, t = threadIdx.x;
  for (int i = t; i < T_; i += 1024) {
    float v = logits[(size_t)b*T_ + i];
    unsigned u = __float_as_uint(v);
    unsigned so = u ^ ((u >> 31) ? 0xFFFFFFFFu : 0x80000000u);
    key[i] = ((unsigned long long)(~so) << 32) | (unsigned)i;
  }
  __syncthreads();
  for (int k = 2; k <= 2048; k <<= 1) {
    for (int j = k >> 1; j > 0; j >>= 1) {
      int i = ((t & ~(j-1)) << 1) | (t & (j-1));
      int ix = i | j;
      unsigned long long a = key[i], c = key[ix];
      bool up = ((i & k) == 0);
      if ((a > c) == up) { key[i] = c; key[ix] = a; }
      __syncthreads();
    }
  }
  unsigned long long a = key[t];
  __syncthreads();
  unsigned i0 = (unsigned)(a & 0xFFFFFFFFu);
  unsigned so = ~(unsigned)(a >> 32);
  unsigned bits = (so & 0x80000000u) ? (so ^ 0x80000000u) : ~so;
  key[t] = ((unsigned long long)i0 << 32) | bits;
  __syncthreads();
  for (int k = 2; k <= 1024; k <<= 1) {
    for (int j = k >> 1; j > 0; j >>= 1) {
      if (t < 512) {
        int i = ((t & ~(j-1)) << 1) | (t & (j-1));
        int ix = i | j;
        unsigned long long a2 = key[i], c2 = key[ix];
        bool up = ((i & k) == 0);
        if ((a2 > c2) == up) { key[i] = c2; key[ix] = a2; }
      }
      __syncthreads();
    }
  }
  idx[(size_t)b*S_ + t] = (int)(key[t] >> 32);
  wts[(size_t)b*S_ + t] = __uint_as_float((unsigned)(key[t] & 0xFFFFFFFFu));
}

// -------- fp32 -> bf16 conversion (weights) --------
__global__ __launch_bounds__(256) void k_cvt(const float* __restrict__ s,
    short* __restrict__ d, int n4) {
  int i = blockIdx.x * 256 + threadIdx.x;
  if (i >= n4) return;
  float4 v = ((const float4*)s)[i];
  short4 o;
  o.x = f2bf(v.x); o.y = f2bf(v.y); o.z = f2bf(v.z); o.w = f2bf(v.w);
  ((short4*)d)[i] = o;
}

// -------- LayerNorm (optionally gathering tokens from x via idx) --------
template<bool GATHER>
__global__ __launch_bounds__(256) void k_ln(const float* __restrict__ x,
    const int* __restrict__ idx, float* __restrict__ hbuf,
    short* __restrict__ obf, const float* __restrict__ g,
    const float* __restrict__ beta) {
  __shared__ float red[8];
  int row = blockIdx.x;
  const float* src;
  if (GATHER) {
    int b = row >> 10, k = row & 1023;
    src = x + ((size_t)b*T_ + idx[b*S_ + k]) * C_;
  } else {
    src = hbuf + (size_t)row * C_;
  }
  int t = threadIdx.x;
  float4 v = *(const float4*)(src + t*4);
  float s  = v.x + v.y + v.z + v.w;
  float s2 = v.x*v.x + v.y*v.y + v.z*v.z + v.w*v.w;
  #pragma unroll
  for (int m = 32; m; m >>= 1) { s += __shfl_xor(s, m); s2 += __shfl_xor(s2, m); }
  int w = t >> 6, lane = t & 63;
  if (lane == 0) { red[w] = s; red[w+4] = s2; }
  __syncthreads();
  s  = red[0]+red[1]+red[2]+red[3];
  s2 = red[4]+red[5]+red[6]+red[7];
  float mu = s * (1.f/(float)C_);
  float var = s2 * (1.f/(float)C_) - mu*mu;
  float rs = rsqrtf(var + 1e-5f);
  int c0 = t*4;
  float4 gw = *(const float4*)(g + c0);
  float4 bw = *(const float4*)(beta + c0);
  short4 o;
  o.x = f2bf((v.x-mu)*rs*gw.x + bw.x);
  o.y = f2bf((v.y-mu)*rs*gw.y + bw.y);
  o.z = f2bf((v.z-mu)*rs*gw.z + bw.z);
  o.w = f2bf((v.w-mu)*rs*gw.w + bw.w);
  *(short4*)(obf + (size_t)row*C_ + c0) = o;
  if (GATHER) *(float4*)(hbuf + (size_t)row*C_ + c0) = v;
}

#define EPI_BF16 0
#define EPI_GELU 1
#define EPI_ADD32 2

// branch-free tanh-form GELU (|err| <= ~4e-4): ~8 VALU ops, no erff
__device__ __forceinline__ float gelu_fast(float v) {
  float z = 0.7978845608f * (v + 0.044715f * v * v * v);
  float e = __expf(2.f * z);
  return v - v * __builtin_amdgcn_rcpf(e + 1.f);
}

// ======== k_gemm4: m97-regime GEMM (unchanged from round 6) ========
template<int BM, int BN, int EPI>
__global__ __launch_bounds__(256) void k_gemm4(
    const short* __restrict__ A, int lda,
    const short* __restrict__ Bp, int ldb,
    void* __restrict__ Cp, int ldc,
    const float* __restrict__ bias,
    int nNt, int Ktot) {
  constexpr int ACH = BM*64/8/256;
  constexpr int BCH = BN*64/8/256;
  __shared__ short As[BM*64];
  __shared__ short Bs[BN*64];
  int nwg = gridDim.x, orig = blockIdx.x;
  int q8 = nwg >> 3, r8 = nwg & 7;
  int xcd = orig & 7, loc = orig >> 3;
  int wg = (xcd < r8 ? xcd*(q8+1) : r8*(q8+1) + (xcd-r8)*q8) + loc;
  int bm = wg / nNt, bn = wg % nNt;
  const short* Ar = A + (size_t)bm*BM*lda;
  const short* Br = Bp + (size_t)bn*BN*ldb;
  constexpr int WM = BM/2, WN = BN/2, FM = WM/16, FN = WN/16;
  int t = threadIdx.x, lane = t & 63, w = t >> 6;
  int wm = w >> 1, wn = w & 1;
  int lr = lane & 15, kq = lane >> 4;
  f32x4 acc[FM][FN] = {};
  for (int k0 = 0; k0 < Ktot; k0 += 64) {
    #pragma unroll
    for (int c = 0; c < ACH; ++c) {
      int ch = c*256 + t;
      int row = ch >> 3, sq = (ch & 7) ^ (row & 7);
      gload_lds16(Ar + (size_t)row*lda + (k0 + sq*8), &As[ch*8]);
    }
    #pragma unroll
    for (int c = 0; c < BCH; ++c) {
      int ch = c*256 + t;
      int row = ch >> 3, sq = (ch & 7) ^ (row & 7);
      gload_lds16(Br + (size_t)row*ldb + (k0 + sq*8), &Bs[ch*8]);
    }
    asm volatile("s_waitcnt vmcnt(0)" ::: "memory");
    __syncthreads();
    bf16x8 af[2][FM], bfv[2][FN];
    #pragma unroll
    for (int ks = 0; ks < 2; ++ks) {
      #pragma unroll
      for (int i = 0; i < FM; ++i) {
        int ra = wm*WM + i*16 + lr;
        af[ks][i] = *(const bf16x8*)&As[ra*64 + ((((ks<<2)+kq) ^ (ra & 7)) << 3)];
      }
      #pragma unroll
      for (int j = 0; j < FN; ++j) {
        int rb = wn*WN + j*16 + lr;
        bfv[ks][j] = *(const bf16x8*)&Bs[rb*64 + ((((ks<<2)+kq) ^ (rb & 7)) << 3)];
      }
    }
    #pragma unroll
    for (int ks = 0; ks < 2; ++ks)
      #pragma unroll
      for (int i = 0; i < FM; ++i)
        #pragma unroll
        for (int j = 0; j < FN; ++j)
          acc[i][j] = __builtin_amdgcn_mfma_f32_16x16x32_bf16(bfv[ks][j], af[ks][i], acc[i][j], 0, 0, 0);
    __syncthreads();
  }
  int mrow0 = bm*BM + wm*WM + lr;
  int ncol0 = bn*BN + wn*WN + (kq << 2);
  #pragma unroll
  for (int i = 0; i < FM; ++i) {
    int row = mrow0 + i*16;
    #pragma unroll
    for (int j = 0; j < FN; ++j) {
      int col = ncol0 + j*16;
      float4 bv = bias ? *(const float4*)(bias + col) : make_float4(0.f,0.f,0.f,0.f);
      float v0 = acc[i][j][0] + bv.x, v1 = acc[i][j][1] + bv.y;
      float v2 = acc[i][j][2] + bv.z, v3 = acc[i][j][3] + bv.w;
      if (EPI == EPI_ADD32) {
        float* Co = (float*)Cp + (size_t)row*ldc + col;
        float4 old = *(float4*)Co;
        old.x += v0; old.y += v1; old.z += v2; old.w += v3;
        *(float4*)Co = old;
      } else {
        if (EPI == EPI_GELU) {
          v0 = gelu_fast(v0); v1 = gelu_fast(v1);
          v2 = gelu_fast(v2); v3 = gelu_fast(v3);
        }
        short4 o; o.x = f2bf(v0); o.y = f2bf(v1); o.z = f2bf(v2); o.w = f2bf(v3);
        *(short4*)((short*)Cp + (size_t)row*ldc + col) = o;
      }
    }
  }
}

// -------- V transpose: qkv[b,s,2C+h*64+d] -> vt[(b*H+h)*64+d][s] --------
__global__ __launch_bounds__(256) void k_vt(const short* __restrict__ qkv,
                                            short* __restrict__ vt) {
  __shared__ short tile[64][65];
  int blk = blockIdx.x;
  int s0 = (blk & 15) << 6;
  int bh = blk >> 4;
  int b = bh >> 4, h = bh & 15;
  const short* src = qkv + (size_t)b*S_*3*C_ + 2*C_ + h*DH_;
  int t = threadIdx.x;
  #pragma unroll
  for (int it = 0; it < 16; ++it) {
    int e = it*256 + t;
    int r = e >> 6, d = e & 63;
    tile[d][r] = src[(size_t)(s0 + r)*3*C_ + d];
  }
  __syncthreads();
  short* dst = vt + (size_t)bh*DH_*S_ + s0;
  #pragma unroll
  for (int it = 0; it < 16; ++it) {
    int e = it*256 + t;
    int d2 = e >> 6, c = e & 63;
    dst[(size_t)d2*S_ + c] = tile[d2][c];
  }
}

// ======== k_fattn v2: fused causal flash attention ========
// Block = (128 q-rows, head); 4 waves x 32 q-rows. KVBLK=64.
// K double-buffered in LDS with 1-tile prefetch (vmcnt drain at NEXT tile's
// head barrier -> HBM latency hidden under QK^T+softmax+PV). V^T read
// directly from global (L2-resident, 8x reuse). P exchange via wave-private
// LDS slice (lgkmcnt fence only, no barrier). 1 barrier per tile.
__global__ __launch_bounds__(256, 4) void k_fattn(
    const short* __restrict__ qkv, const short* __restrict__ vt,
    short* __restrict__ attnb) {
  __shared__ short Ks[2][64*64];     // 2 x 8KB (also Q staging = 16KB)
  __shared__ short Ps[4][32*72];     // wave-private P slice, +8 pad (18KB)
  int qt = blockIdx.x;               // 0..7
  int bh = blockIdx.y;               // b*16+h
  int b = bh >> 4, h = bh & 15;
  int t = threadIdx.x, lane = t & 63, w = t >> 6;
  int lr = lane & 15, kq = lane >> 4;
  const short* Qbase = qkv + ((size_t)b*S_ + qt*128)*3*C_ + h*DH_;
  const short* Kbase = qkv + (size_t)b*S_*3*C_ + C_ + h*DH_;
  const short* Vtb   = vt + (size_t)bh*DH_*S_;

  // ---- stage Q tile (128x64 = 16KB over both Ks halves), read frags ----
  short* Qs = &Ks[0][0];
  #pragma unroll
  for (int c = 0; c < 4; ++c) {
    int ch = c*256 + t;
    int row = ch >> 3, sq = (ch & 7) ^ (row & 7);
    gload_lds16(Qbase + (size_t)row*3*C_ + sq*8, &Qs[ch*8]);
  }
  asm volatile("s_waitcnt vmcnt(0)" ::: "memory");
  __builtin_amdgcn_s_barrier();
  bf16x8 qf[2][2];
  #pragma unroll
  for (int ks = 0; ks < 2; ++ks)
    #pragma unroll
    for (int i = 0; i < 2; ++i) {
      int rq = w*32 + i*16 + lr;
      qf[ks][i] = *(const bf16x8*)&Qs[rq*64 + ((((ks<<2)+kq) ^ (rq & 7)) << 3)];
    }
  asm volatile("s_waitcnt lgkmcnt(0)" ::: "memory");  // qf reads done before K DMA
  __builtin_amdgcn_sched_barrier(0);
  __builtin_amdgcn_s_barrier();

  auto stageK = [&](int buf, int jj) {
    #pragma unroll
    for (int c = 0; c < 2; ++c) {
      int ch = c*256 + t;
      int row = ch >> 3, sq = (ch & 7) ^ (row & 7);
      gload_lds16(Kbase + (size_t)(jj*64 + row)*3*C_ + sq*8, &Ks[buf][ch*8]);
    }
  };
  stageK(0, 0);   // prologue prefetch

  f32x4 o[2][4] = {};
  float m_i[2] = {-3.0e38f, -3.0e38f};
  float l_i[2] = {0.f, 0.f};
  short* Pw = &Ps[w][0];
  int NTl = 2*qt + 2;

  for (int jj = 0; jj < NTl; ++jj) {
    int cur = jj & 1;
    // head: own prefetch drained + all waves' DMA visible
    asm volatile("s_waitcnt vmcnt(0)" ::: "memory");
    __builtin_amdgcn_s_barrier();
    if (jj + 1 < NTl) stageK(cur ^ 1, jj + 1);   // prefetch next tile

    // S = Q @ K^T  (32 q-rows x 64 kv per wave)
    f32x4 s[2][4] = {};
    #pragma unroll
    for (int ks = 0; ks < 2; ++ks) {
      bf16x8 kf[4];
      #pragma unroll
      for (int j = 0; j < 4; ++j) {
        int rk = j*16 + lr;
        kf[j] = *(const bf16x8*)&Ks[cur][rk*64 + ((((ks<<2)+kq) ^ (rk & 7)) << 3)];
      }
      #pragma unroll
      for (int i = 0; i < 2; ++i)
        #pragma unroll
        for (int j = 0; j < 4; ++j)
          s[i][j] = __builtin_amdgcn_mfma_f32_16x16x32_bf16(kf[j], qf[ks][i], s[i][j], 0, 0, 0);
    }

    // online softmax (rows lane-local per (i,lr); reduce over kq via shfl)
    bool maskTile = (jj >= 2*qt);
    #pragma unroll
    for (int i = 0; i < 2; ++i) {
      int qrow = qt*128 + w*32 + i*16 + lr;
      float rmax = -3.0e38f;
      #pragma unroll
      for (int j = 0; j < 4; ++j)
        #pragma unroll
        for (int r = 0; r < 4; ++r) {
          int colg = jj*64 + j*16 + (kq<<2) + r;
          float v = s[i][j][r] * 0.125f;
          if (maskTile && colg > qrow) v = -3.0e38f;
          s[i][j][r] = v;
          rmax = fmaxf(rmax, v);
        }
      rmax = fmaxf(rmax, __shfl_xor(rmax, 16));
      rmax = fmaxf(rmax, __shfl_xor(rmax, 32));
      float mnew = fmaxf(m_i[i], rmax);
      float alpha = __expf(m_i[i] - mnew);
      m_i[i] = mnew;
      float rsum = 0.f;
      #pragma unroll
      for (int j = 0; j < 4; ++j)
        #pragma unroll
        for (int r = 0; r < 4; ++r) {
          float pv = __expf(s[i][j][r] - mnew);
          s[i][j][r] = pv;
          rsum += pv;
        }
      rsum += __shfl_xor(rsum, 16);
      rsum += __shfl_xor(rsum, 32);
      l_i[i] = l_i[i]*alpha + rsum;
      #pragma unroll
      for (int jo = 0; jo < 4; ++jo)
        #pragma unroll
        for (int r = 0; r < 4; ++r)
          o[i][jo][r] *= alpha;
    }

    // P (acc layout) -> wave-private LDS slice
    #pragma unroll
    for (int i = 0; i < 2; ++i)
      #pragma unroll
      for (int j = 0; j < 4; ++j) {
        short4 pk;
        pk.x = f2bf(s[i][j][0]); pk.y = f2bf(s[i][j][1]);
        pk.z = f2bf(s[i][j][2]); pk.w = f2bf(s[i][j][3]);
        *(short4*)&Pw[(i*16 + lr)*72 + j*16 + (kq<<2)] = pk;
      }
    asm volatile("s_waitcnt lgkmcnt(0)" ::: "memory");  // writes land before reads
    __builtin_amdgcn_sched_barrier(0);

    // O += P @ V  (V^T fragments straight from global/L2)
    #pragma unroll
    for (int sstep = 0; sstep < 2; ++sstep) {
      bf16x8 pf[2], vf[4];
      #pragma unroll
      for (int i = 0; i < 2; ++i)
        pf[i] = *(const bf16x8*)&Pw[(i*16 + lr)*72 + sstep*32 + (kq<<3)];
      #pragma unroll
      for (int jo = 0; jo < 4; ++jo)
        vf[jo] = *(const bf16x8*)&Vtb[(size_t)(jo*16 + lr)*S_ + jj*64 + sstep*32 + (kq<<3)];
      #pragma unroll
      for (int i = 0; i < 2; ++i)
        #pragma unroll
        for (int jo = 0; jo < 4; ++jo)
          o[i][jo] = __builtin_amdgcn_mfma_f32_16x16x32_bf16(vf[jo], pf[i], o[i][jo], 0, 0, 0);
    }
    // no tail barrier: next head barrier orders Ks[cur] reuse
  }

  // epilogue: attn[b, q, h*64+d] = O / l
  #pragma unroll
  for (int i = 0; i < 2; ++i) {
    float inv = 1.f / l_i[i];
    int q = qt*128 + w*32 + i*16 + lr;
    #pragma unroll
    for (int jo = 0; jo < 4; ++jo) {
      int d = jo*16 + (kq<<2);
      short4 ov;
      ov.x = f2bf(o[i][jo][0]*inv); ov.y = f2bf(o[i][jo][1]*inv);
      ov.z = f2bf(o[i][jo][2]*inv); ov.w = f2bf(o[i][jo][3]*inv);
      *(short4*)&attnb[((size_t)b*S_ + q)*C_ + h*DH_ + d] = ov;
    }
  }
}

// -------- out = x everywhere --------
__global__ void k_copy(const float* __restrict__ src, float* __restrict__ dst,
                       size_t n4) {
  size_t i = (size_t)blockIdx.x*256 + threadIdx.x;
  size_t stride = (size_t)gridDim.x*256;
  for (; i < n4; i += stride) ((float4*)dst)[i] = ((const float4*)src)[i];
}

// -------- out[selected row] = x + weight * h --------
__global__ __launch_bounds__(256) void k_scatter(const float* __restrict__ x,
    const int* __restrict__ idx, const float* __restrict__ wts,
    const float* __restrict__ hbuf, float* __restrict__ out) {
  int row = blockIdx.x;
  int b = row >> 10, k = row & 1023;
  int tk = idx[(size_t)b*S_ + k];
  float wv = wts[(size_t)b*S_ + k];
  size_t o  = ((size_t)b*T_ + tk)*C_ + threadIdx.x*4;
  size_t hs = (size_t)row*C_ + threadIdx.x*4;
  float4 xv = *(const float4*)(x + o);
  float4 hv = *(const float4*)(hbuf + hs);
  xv.x += wv*hv.x; xv.y += wv*hv.y; xv.z += wv*hv.z; xv.w += wv*hv.w;
  *(float4*)(out + o) = xv;
}

extern "C" void kernel_launch(void* const* d_in, const int* in_sizes, int n_in,
                              void* d_out, int out_size, void* d_ws, size_t ws_size,
                              hipStream_t stream) {
  const float* x     = (const float*)d_in[0];
  const float* wrt   = (const float*)d_in[1];
  const float* ln1w  = (const float*)d_in[2];
  const float* ln1b  = (const float*)d_in[3];
  const float* wqkv  = (const float*)d_in[4];
  const float* bqkv  = (const float*)d_in[5];
  const float* wo    = (const float*)d_in[6];
  const float* bo    = (const float*)d_in[7];
  const float* ln2w  = (const float*)d_in[8];
  const float* ln2b  = (const float*)d_in[9];
  const float* wfc   = (const float*)d_in[10];
  const float* bfc   = (const float*)d_in[11];
  const float* wproj = (const float*)d_in[12];
  const float* bproj = (const float*)d_in[13];
  float* out = (float*)d_out;

  char* p = (char*)d_ws;
  auto alloc = [&](size_t bytes) {
    char* r = p; p += (bytes + 255) & ~(size_t)255; return r;
  };
  float* logits = (float*)alloc((size_t)B_*T_*4);
  int*   idx    = (int*)  alloc((size_t)B_*S_*4);
  float* wts    = (float*)alloc((size_t)B_*S_*4);
  float* hbuf   = (float*)alloc((size_t)M_*C_*4);
  short* abuf   = (short*)alloc((size_t)M_*C_*2);
  short* qkvb   = (short*)alloc((size_t)M_*3*C_*2);
  short* vtb    = (short*)alloc((size_t)B_*H_*DH_*S_*2);
  short* attnb  = (short*)alloc((size_t)M_*C_*2);
  short* fcb    = (short*)alloc((size_t)M_*DFF_*2);
  short* wqkvb  = (short*)alloc((size_t)3*C_*C_*2);
  short* wob    = (short*)alloc((size_t)C_*C_*2);
  short* wfcb   = (short*)alloc((size_t)DFF_*C_*2);
  short* wprojb = (short*)alloc((size_t)C_*DFF_*2);
  if (ws_size < (size_t)(p - (char*)d_ws)) return;

  k_cvt<<<dim3(3*C_*C_/4/256), dim3(256), 0, stream>>>(wqkv, wqkvb, 3*C_*C_/4);
  k_cvt<<<dim3(C_*C_/4/256),   dim3(256), 0, stream>>>(wo, wob, C_*C_/4);
  k_cvt<<<dim3(DFF_*C_/4/256), dim3(256), 0, stream>>>(wfc, wfcb, DFF_*C_/4);
  k_cvt<<<dim3(C_*DFF_/4/256), dim3(256), 0, stream>>>(wproj, wprojb, C_*DFF_/4);

  k_router<<<dim3(B_*T_/4), dim3(256), 0, stream>>>(x, wrt, logits);
  k_topk<<<dim3(B_), dim3(1024), 0, stream>>>(logits, idx, wts);

  k_ln<true><<<dim3(M_), dim3(256), 0, stream>>>(x, idx, hbuf, abuf, ln1w, ln1b);

  // QKV: [8192,1024] @ [3072,1024]^T
  k_gemm4<128,128,EPI_BF16>
    <<<dim3((M_/128)*(3*C_/128)), dim3(256), 0, stream>>>(
      abuf, C_, wqkvb, C_, qkvb, 3*C_, bqkv, 3*C_/128, C_);

  k_vt<<<dim3(B_*H_*(S_/64)), dim3(256), 0, stream>>>(qkvb, vtb);

  // fused causal flash attention
  k_fattn<<<dim3(S_/128, B_*H_), dim3(256), 0, stream>>>(qkvb, vtb, attnb);

  // h += attn @ w_o^T + b_o
  k_gemm4<128,128,EPI_ADD32>
    <<<dim3((M_/128)*(C_/128)), dim3(256), 0, stream>>>(
      attnb, C_, wob, C_, hbuf, C_, bo, C_/128, C_);

  k_ln<false><<<dim3(M_), dim3(256), 0, stream>>>(nullptr, nullptr, hbuf, abuf, ln2w, ln2b);

  // fc = gelu(m @ w_fc^T + b_fc)
  k_gemm4<128,128,EPI_GELU>
    <<<dim3((M_/128)*(DFF_/128)), dim3(256), 0, stream>>>(
      abuf, C_, wfcb, C_, fcb, DFF_, bfc, DFF_/128, C_);

  // h += fc @ w_proj^T + b_proj
  k_gemm4<128,128,EPI_ADD32>
    <<<dim3((M_/128)*(C_/128)), dim3(256), 0, stream>>>(
      fcb, DFF_, wprojb, DFF_, hbuf, C_, bproj, C_/128, DFF_);

  k_copy<<<dim3(2048), dim3(256), 0, stream>>>(x, out, (size_t)B_*T_*C_/4);
  k_scatter<<<dim3(M_), dim3(256), 0, stream>>>(x, idx, wts, hbuf, out);
}